// Round 15
// baseline (1586.663 us; speedup 1.0000x reference)
//
#include <hip/hip_runtime.h>
#include <math.h>
#include <stdint.h>

#define N_C 60000
#define N_V 256
#define CH 128
#define NH 4
#define HD 32
#define NL 3
#define NE1 600000
#define NE2 240000

#define CDIV(a,b) (((a)+(b)-1)/(b))
#define EPB 1024   // elems per block in counting-sort kernels

typedef __attribute__((ext_vector_type(8))) short bf16x8;
typedef __attribute__((ext_vector_type(4))) float f32x4;

__device__ __forceinline__ float gelu_tanh(float x) {
    float x3 = x * x * x;
    float t = tanhf(0.7978845608028654f * (x + 0.044715f * x3));
    return 0.5f * x * (1.0f + t);
}

__device__ __forceinline__ float dot8(float4 qa, float4 qb, float4 ka, float4 kb) {
    float d = qa.x * ka.x;
    d = fmaf(qa.y, ka.y, d);
    d = fmaf(qa.z, ka.z, d);
    d = fmaf(qa.w, ka.w, d);
    d = fmaf(qb.x, kb.x, d);
    d = fmaf(qb.y, kb.y, d);
    d = fmaf(qb.z, kb.z, d);
    d = fmaf(qb.w, kb.w, d);
    return d;
}

// ---------------- bf16x3 split helpers ----------------------------------------
__device__ __forceinline__ short f2bf(float f) {
    uint32_t u = __builtin_bit_cast(uint32_t, f);
    u = (u + 0x7FFFu + ((u >> 16) & 1u)) >> 16;
    return (short)u;
}
__device__ __forceinline__ float bf2f(short s) {
    uint32_t u = ((uint32_t)(uint16_t)s) << 16;
    return __builtin_bit_cast(float, u);
}
__device__ __forceinline__ void split3(float v, short& h, short& m, short& l) {
    h = f2bf(v); float vh = bf2f(h);
    float r1 = v - vh;
    m = f2bf(r1); float vm = bf2f(m);
    l = f2bf(r1 - vm);
}

// ---------------- weight composition: W~q = Wq . arel  (prel/sqrt(D) folded) ---
__global__ __launch_bounds__(256) void compose_wq(
    const float* __restrict__ Wq, const float* __restrict__ bq,
    const float* __restrict__ arel, const float* __restrict__ prel,
    float* __restrict__ WQT, float* __restrict__ BQT)
{
    int gid = blockIdx.x * blockDim.x + threadIdx.x;
    const int total = NL * 2 * (CH + 1) * CH;
    if (gid >= total) return;
    int li2 = gid / ((CH + 1) * CH);
    int rem = gid % ((CH + 1) * CH);
    int c   = rem / CH;          // 0..CH ; CH => bias row
    int col = rem % CH;
    int h = col >> 5, d = col & 31;
    const float* ar = arel + (li2 * NH + h) * (HD * HD) + d * HD;  // [e]
    float scale = prel[li2 * NH + h] * 0.17677669529663687f;       // prel/sqrt(32)
    const float* src = (c < CH) ? (Wq + ((size_t)li2 * CH + c) * CH + h * HD)
                                : (bq + li2 * CH + h * HD);
    float acc = 0.f;
    #pragma unroll
    for (int e = 0; e < HD; e++) acc = fmaf(src[e], ar[e], acc);
    acc *= scale;
    if (c < CH) WQT[((size_t)li2 * CH + c) * CH + col] = acc;
    else        BQT[li2 * CH + col] = acc;
}

// ---------------- weight split+PACK: fragment-ordered bf16x3 -------------------
// WP layout per layer: [jw][lvl][kb][nt][lane][8]
__global__ __launch_bounds__(256) void split_w(
    const float* __restrict__ WQT, const float* __restrict__ Wk,
    const float* __restrict__ Wv, short* __restrict__ WP)
{
    int gid = blockIdx.x * blockDim.x + threadIdx.x;
    const int total = NL * 3 * CH * CH;
    if (gid >= total) return;
    int li  = gid / (3 * CH * CH);
    int rem = gid % (3 * CH * CH);
    int jw  = rem / (CH * CH);
    int idx = rem % (CH * CH);
    int n = idx >> 7, k = idx & 127;
    const float* src = (jw == 0) ? WQT + (size_t)(li * 2) * CH * CH
                     : (jw == 1) ? Wk + (size_t)(li * 2) * CH * CH
                                 : Wv + (size_t)(li * 2) * CH * CH;
    float v = src[k * CH + n];   // B^T[n][k]
    short h, m, l;
    split3(v, h, m, l);
    int kb = k >> 5, quad = (k >> 3) & 3, j = k & 7;
    int nt = n >> 4, mm = n & 15;
    int lane = quad * 16 + mm;
    size_t frag = (size_t)((kb * 8 + nt) * 64 + lane) * 8 + j;
    size_t base = (size_t)(li * 9 + jw * 3) * (CH * CH);
    WP[base + frag]                 = h;
    WP[base + CH * CH + frag]       = m;
    WP[base + 2 * CH * CH + frag]   = l;
}

// ---------------- activation split (layer 0) -----------------------------------
__global__ __launch_bounds__(256) void split_x(const float* __restrict__ x, int n,
    short* __restrict__ xh, short* __restrict__ xm, short* __restrict__ xl)
{
    int i = blockIdx.x * 256 + threadIdx.x;
    if (i >= n) return;
    short h, m, l;
    split3(x[i], h, m, l);
    xh[i] = h; xm[i] = m; xl[i] = l;
}

// ================= CSR build: two-level LDS counting sort =====================
__global__ __launch_bounds__(256) void bucket_hist(const int* __restrict__ dst, int E,
                                                   int shift, int* __restrict__ bhist)
{
    __shared__ int h[256];
    int t = threadIdx.x;
    h[t] = 0;
    __syncthreads();
    int i0 = blockIdx.x * EPB, i1 = min(i0 + EPB, E);
    for (int i = i0 + t; i < i1; i += 256)
        atomicAdd(&h[(dst[i] >> shift) & 255], 1);
    __syncthreads();
    if (h[t] > 0) atomicAdd(&bhist[t], h[t]);
}

__global__ __launch_bounds__(256) void scan256(const int* __restrict__ h,
                                               int* __restrict__ base, int* __restrict__ cur)
{
    __shared__ int p[256];
    int t = threadIdx.x;
    int v = h[t];
    p[t] = v;
    __syncthreads();
    for (int off = 1; off < 256; off <<= 1) {
        int u = (t >= off) ? p[t - off] : 0;
        __syncthreads();
        p[t] += u;
        __syncthreads();
    }
    base[t] = p[t] - v;
    cur[t]  = p[t] - v;
    if (t == 255) base[256] = p[255];
}

template<bool PAIR>
__global__ __launch_bounds__(256) void partition_edges(
    const int* __restrict__ src, const int* __restrict__ dst, int E, int shift,
    int* __restrict__ cur, int2* __restrict__ tmp_pair, int* __restrict__ out_src)
{
    __shared__ int cnt[256], base[256], cnt2[256];
    int t = threadIdx.x;
    cnt[t] = 0; cnt2[t] = 0;
    __syncthreads();
    int i0 = blockIdx.x * EPB, i1 = min(i0 + EPB, E);
    for (int i = i0 + t; i < i1; i += 256)
        atomicAdd(&cnt[(dst[i] >> shift) & 255], 1);
    __syncthreads();
    if (cnt[t] > 0) base[t] = atomicAdd(&cur[t], cnt[t]);
    __syncthreads();
    for (int i = i0 + t; i < i1; i += 256) {
        int d = dst[i];
        int dig = (d >> shift) & 255;
        int r = atomicAdd(&cnt2[dig], 1);
        int pos = base[dig] + r;
        if constexpr (PAIR) tmp_pair[pos] = make_int2(src[i], d);
        else                out_src[pos] = src[i];
    }
}

__global__ __launch_bounds__(256) void bucket_finalize(
    const int2* __restrict__ tmp, const int* __restrict__ bbase, int n, int NE,
    int* __restrict__ rs, int* __restrict__ csr)
{
    __shared__ int cnt[256], pre[256], cnt2[256];
    int b = blockIdx.x, t = threadIdx.x;
    int s0 = bbase[b], s1 = bbase[b + 1];
    cnt[t] = 0; cnt2[t] = 0;
    __syncthreads();
    for (int i = s0 + t; i < s1; i += 256)
        atomicAdd(&cnt[tmp[i].y & 255], 1);
    __syncthreads();
    int v = cnt[t];
    pre[t] = v;
    __syncthreads();
    for (int off = 1; off < 256; off <<= 1) {
        int u = (t >= off) ? pre[t - off] : 0;
        __syncthreads();
        pre[t] += u;
        __syncthreads();
    }
    pre[t] -= v;   // exclusive
    __syncthreads();
    int dstid = b * 256 + t;
    if (dstid < n) rs[dstid] = s0 + pre[t];
    if (b == 0 && t == 0) rs[n] = NE;
    for (int i = s0 + t; i < s1; i += 256) {
        int2 e = tmp[i];
        int low = e.y & 255;
        int r = atomicAdd(&cnt2[low], 1);
        csr[s0 + pre[low] + r] = e.x;
    }
}

// ---------------- bf16x3 MFMA qkv GEMM: LDS-staged packed B fragments ----------
// Block = 4 waves x 16 rows. Per (jw,kb): stage 24 KB fragment slab to LDS
// (shared by all 4 waves), then each wave reads frags via ds_read_b128.
__global__ __launch_bounds__(256) void gemm_qkv_mfma(
    const short* __restrict__ XH, const short* __restrict__ XM, const short* __restrict__ XL,
    const short* __restrict__ WP,   // this layer's packed [jw][lvl][kb][nt][lane][8]
    const float* __restrict__ b0, const float* __restrict__ b1, const float* __restrict__ b2,
    float* __restrict__ out, int M)
{
    __shared__ short WS[3 * 4096];   // 24 KB: [lvl][nt][lane][8] for current (jw,kb)
    int tid = threadIdx.x;
    int lane = tid & 63, wid = tid >> 6;
    int r0 = blockIdx.x * 64 + wid * 16;
    bool active = (r0 < M);
    int m = lane & 15, quad = lane >> 4;
    int arow = active ? min(r0 + m, M - 1) : 0;
    // hoisted A fragments (identical for all 3 weight matrices)
    bf16x8 ah[4], am4[4], al[4];
    #pragma unroll
    for (int kb = 0; kb < 4; kb++) {
        int aoff = arow * CH + kb * 32 + quad * 8;
        ah[kb]  = *(const bf16x8*)(XH + aoff);
        am4[kb] = *(const bf16x8*)(XM + aoff);
        al[kb]  = *(const bf16x8*)(XL + aoff);
    }
    const float* biases[3] = {b0, b1, b2};
    for (int jw = 0; jw < 3; jw++) {
        f32x4 acc[8] = {};
        for (int kb = 0; kb < 4; kb++) {
            __syncthreads();
            // stage 3 limbs x 4096 shorts (each 8KB contiguous) -> 2 float4/thread/limb
            #pragma unroll
            for (int lvl = 0; lvl < 3; lvl++) {
                const float4* s4 = (const float4*)(WP + ((size_t)(jw * 3 + lvl)) * (CH * CH) + kb * 4096);
                float4* d4 = (float4*)(WS + lvl * 4096);
                d4[tid]       = s4[tid];
                d4[tid + 256] = s4[tid + 256];
            }
            __syncthreads();
            #pragma unroll
            for (int nt = 0; nt < 8; nt++) {
                int boff = nt * 512 + lane * 8;
                bf16x8 bh = *(const bf16x8*)(WS + boff);
                bf16x8 bm = *(const bf16x8*)(WS + 4096 + boff);
                bf16x8 bl = *(const bf16x8*)(WS + 8192 + boff);
                acc[nt] = __builtin_amdgcn_mfma_f32_16x16x32_bf16(ah[kb], bh, acc[nt], 0, 0, 0);
                acc[nt] = __builtin_amdgcn_mfma_f32_16x16x32_bf16(ah[kb], bm, acc[nt], 0, 0, 0);
                acc[nt] = __builtin_amdgcn_mfma_f32_16x16x32_bf16(am4[kb], bh, acc[nt], 0, 0, 0);
                acc[nt] = __builtin_amdgcn_mfma_f32_16x16x32_bf16(am4[kb], bm, acc[nt], 0, 0, 0);
                acc[nt] = __builtin_amdgcn_mfma_f32_16x16x32_bf16(ah[kb], bl, acc[nt], 0, 0, 0);
                acc[nt] = __builtin_amdgcn_mfma_f32_16x16x32_bf16(al[kb], bh, acc[nt], 0, 0, 0);
            }
        }
        if (active) {
            const float* bias = biases[jw];
            #pragma unroll
            for (int nt = 0; nt < 8; nt++) {
                int col = nt * 16 + m;
                float bc = bias[col];
                #pragma unroll
                for (int reg = 0; reg < 4; reg++) {
                    int r = r0 + quad * 4 + reg;
                    if (r < M) out[(size_t)r * 384 + jw * 128 + col] = acc[nt][reg] + bc;
                }
            }
        }
    }
}

// ---------------- fp32 GEMM, split cols, + fused projections + bf16x3 emit -----
__global__ __launch_bounds__(256) void gemm128(
    const float* __restrict__ A, int lda, const float* __restrict__ W,
    const float* __restrict__ bias, float* out, int M,
    const float* __restrict__ gate, const float* __restrict__ xold,
    const float* __restrict__ wk_o, const float* __restrict__ bk_o, float* __restrict__ ko,
    const float* __restrict__ wv_o, const float* __restrict__ bv_o, float* __restrict__ vo,
    short* __restrict__ xh, short* __restrict__ xm, short* __restrict__ xl)
{
    __shared__ float As[64][36];    // 9 KB (32-wide k-tile, +4 pad)
    __shared__ float Bs[32][128];   // 16 KB
    int tid = threadIdx.x;
    int row0 = blockIdx.x * 64;
    int tx = tid & 15;
    int ty = tid >> 4;
    float acc[4][8] = {};
    for (int k0 = 0; k0 < 128; k0 += 32) {
        __syncthreads();
        #pragma unroll
        for (int i = 0; i < 2; i++) {
            int slot = tid + i * 256;            // [0,512) float4 slots
            int r = slot >> 3, kq = slot & 7;
            int rr = row0 + r;
            float4 v = make_float4(0.f, 0.f, 0.f, 0.f);
            if (rr < M) v = *(const float4*)(A + (size_t)rr * lda + k0 + kq * 4);
            *(float4*)&As[r][kq * 4] = v;
        }
        #pragma unroll
        for (int i = 0; i < 4; i++) {
            int slot = tid + i * 256;            // [0,1024)
            int kr = slot >> 5, cq = slot & 31;
            *(float4*)&Bs[kr][cq * 4] = *(const float4*)(W + (size_t)(k0 + kr) * 128 + cq * 4);
        }
        __syncthreads();
        #pragma unroll
        for (int k4 = 0; k4 < 32; k4 += 4) {
            float4 av[4];
            #pragma unroll
            for (int i = 0; i < 4; i++)
                av[i] = *(const float4*)&As[ty * 4 + i][k4];
            #pragma unroll
            for (int kk = 0; kk < 4; kk++) {
                float4 bl = *(const float4*)&Bs[k4 + kk][tx * 4];
                float4 bh = *(const float4*)&Bs[k4 + kk][64 + tx * 4];
                float bb[8] = {bl.x, bl.y, bl.z, bl.w, bh.x, bh.y, bh.z, bh.w};
                #pragma unroll
                for (int i = 0; i < 4; i++) {
                    float a = ((const float*)&av[i])[kk];
                    #pragma unroll
                    for (int j = 0; j < 8; j++)
                        acc[i][j] = fmaf(a, bb[j], acc[i][j]);
                }
            }
        }
    }
    float g = 1.f, og = 0.f;
    if (gate != nullptr) { g = 1.f / (1.f + expf(-gate[0])); og = 1.f - g; }
    float wkr[8], wvr[8];
    if (wk_o != nullptr) {
        #pragma unroll
        for (int j = 0; j < 4; j++) {
            wkr[j]     = wk_o[tx * 4 + j];
            wkr[4 + j] = wk_o[64 + tx * 4 + j];
        }
    }
    if (wv_o != nullptr) {
        #pragma unroll
        for (int j = 0; j < 4; j++) {
            wvr[j]     = wv_o[tx * 4 + j];
            wvr[4 + j] = wv_o[64 + tx * 4 + j];
        }
    }
    #pragma unroll
    for (int i = 0; i < 4; i++) {
        int r = row0 + ty * 4 + i;
        if (r >= M) continue;   // uniform across each 16-lane group
        float vals[8];
        #pragma unroll
        for (int j = 0; j < 4; j++) {
            float v0 = acc[i][j]     + bias[tx * 4 + j];
            float v1 = acc[i][4 + j] + bias[64 + tx * 4 + j];
            if (gate != nullptr) {
                v0 = g * v0 + og * xold[(size_t)r * 128 + tx * 4 + j];
                v1 = g * v1 + og * xold[(size_t)r * 128 + 64 + tx * 4 + j];
            }
            vals[j] = v0;
            vals[4 + j] = v1;
        }
        float* op = out + (size_t)r * 128;
        *(float4*)(op + tx * 4)      = make_float4(vals[0], vals[1], vals[2], vals[3]);
        *(float4*)(op + 64 + tx * 4) = make_float4(vals[4], vals[5], vals[6], vals[7]);
        if (xh != nullptr) {
            short h4[8], m4[8], l4[8];
            #pragma unroll
            for (int j = 0; j < 8; j++) split3(vals[j], h4[j], m4[j], l4[j]);
            size_t o0 = (size_t)r * 128 + tx * 4;
            size_t o1 = (size_t)r * 128 + 64 + tx * 4;
            *(short4*)(xh + o0) = make_short4(h4[0], h4[1], h4[2], h4[3]);
            *(short4*)(xh + o1) = make_short4(h4[4], h4[5], h4[6], h4[7]);
            *(short4*)(xm + o0) = make_short4(m4[0], m4[1], m4[2], m4[3]);
            *(short4*)(xm + o1) = make_short4(m4[4], m4[5], m4[6], m4[7]);
            *(short4*)(xl + o0) = make_short4(l4[0], l4[1], l4[2], l4[3]);
            *(short4*)(xl + o1) = make_short4(l4[4], l4[5], l4[6], l4[7]);
        }
        if (wk_o != nullptr) {
            float pk = 0.f, pv = 0.f;
            #pragma unroll
            for (int j = 0; j < 8; j++) pk = fmaf(vals[j], wkr[j], pk);
            if (wv_o != nullptr) {
                #pragma unroll
                for (int j = 0; j < 8; j++) pv = fmaf(vals[j], wvr[j], pv);
            }
            #pragma unroll
            for (int off = 1; off < 16; off <<= 1) {
                pk += __shfl_xor(pk, off, 64);
                if (wv_o != nullptr) pv += __shfl_xor(pv, off, 64);
            }
            if (tx == 0) {
                ko[r] = pk + bk_o[0];
                if (wv_o != nullptr) vo[r] = pv + bv_o[0];
            }
        }
    }
}

// ---------------- group-of-16 edge accumulation (4 edges in flight + 2x unroll)
__device__ __forceinline__ void accum_g16(
    const float* __restrict__ xqkv, const int* __restrict__ csr,
    int e0, int e1, int g, float4 qa, float4 qb, float& s_io, float acc[8])
{
    float s = 0.f;
    int e = e0 + g;
    for (; e + 4 < e1; e += 8) {
        int i0 = csr[e], i1 = csr[e + 4];
        const float* p0 = xqkv + (size_t)i0 * 384 + 128 + ((threadIdx.x & 15) * 8);
        const float* p1 = xqkv + (size_t)i1 * 384 + 128 + ((threadIdx.x & 15) * 8);
        float4 k0a = *(const float4*)p0,         k0b = *(const float4*)(p0 + 4);
        float4 v0a = *(const float4*)(p0 + 128), v0b = *(const float4*)(p0 + 132);
        float4 k1a = *(const float4*)p1,         k1b = *(const float4*)(p1 + 4);
        float4 v1a = *(const float4*)(p1 + 128), v1b = *(const float4*)(p1 + 132);
        float d0 = dot8(qa, qb, k0a, k0b);
        float d1 = dot8(qa, qb, k1a, k1b);
        d0 += __shfl_xor(d0, 1, 64); d1 += __shfl_xor(d1, 1, 64);
        d0 += __shfl_xor(d0, 2, 64); d1 += __shfl_xor(d1, 2, 64);
        float w0 = __expf(d0), w1 = __expf(d1);
        s += w0 + w1;
        acc[0] = fmaf(w0, v0a.x, acc[0]); acc[0] = fmaf(w1, v1a.x, acc[0]);
        acc[1] = fmaf(w0, v0a.y, acc[1]); acc[1] = fmaf(w1, v1a.y, acc[1]);
        acc[2] = fmaf(w0, v0a.z, acc[2]); acc[2] = fmaf(w1, v1a.z, acc[2]);
        acc[3] = fmaf(w0, v0a.w, acc[3]); acc[3] = fmaf(w1, v1a.w, acc[3]);
        acc[4] = fmaf(w0, v0b.x, acc[4]); acc[4] = fmaf(w1, v1b.x, acc[4]);
        acc[5] = fmaf(w0, v0b.y, acc[5]); acc[5] = fmaf(w1, v1b.y, acc[5]);
        acc[6] = fmaf(w0, v0b.z, acc[6]); acc[6] = fmaf(w1, v1b.z, acc[6]);
        acc[7] = fmaf(w0, v0b.w, acc[7]); acc[7] = fmaf(w1, v1b.w, acc[7]);
    }
    if (e < e1) {
        int i0 = csr[e];
        const float* p0 = xqkv + (size_t)i0 * 384 + 128 + ((threadIdx.x & 15) * 8);
        float4 k0a = *(const float4*)p0,         k0b = *(const float4*)(p0 + 4);
        float4 v0a = *(const float4*)(p0 + 128), v0b = *(const float4*)(p0 + 132);
        float d0 = dot8(qa, qb, k0a, k0b);
        d0 += __shfl_xor(d0, 1, 64);
        d0 += __shfl_xor(d0, 2, 64);
        float w0 = __expf(d0);
        s += w0;
        acc[0] = fmaf(w0, v0a.x, acc[0]);
        acc[1] = fmaf(w0, v0a.y, acc[1]);
        acc[2] = fmaf(w0, v0a.z, acc[2]);
        acc[3] = fmaf(w0, v0a.w, acc[3]);
        acc[4] = fmaf(w0, v0b.x, acc[4]);
        acc[5] = fmaf(w0, v0b.y, acc[5]);
        acc[6] = fmaf(w0, v0b.z, acc[6]);
        acc[7] = fmaf(w0, v0b.w, acc[7]);
    }
    s_io = s;
}

// ---------------- unified attention: cv blocks [0,256) + cc blocks -------------
__global__ __launch_bounds__(256) void attn_uni(
    float* xqkv,
    const float* __restrict__ xv, const float* __restrict__ wqt,
    const float* __restrict__ bqt,
    const int* __restrict__ rs_cc, const int* __restrict__ csr_cc,
    const int* __restrict__ rs_cv, const int* __restrict__ csr_cv,
    const float* __restrict__ mrel_cc, const float* __restrict__ mrel_cv,
    float* __restrict__ aggv, int n_c)
{
    __shared__ float smem[800];   // 3.2 KB, carved per role
    int lane = threadIdx.x & 63, wid = threadIdx.x >> 6;
    int g = lane >> 4, j = lane & 15;

    if (blockIdx.x < N_V) {
        // ---------------- cv node ----------------
        int node = blockIdx.x;
        float* qrow = smem;          // [128]
        float* sm_s = smem + 128;    // [4][4]
        float* sm_a = smem + 144;    // [4][128]
        float* orow = smem + 656;    // [144]
        if (wid < 2) {
            int col = wid * 64 + lane;
            float a = bqt[col];
            const float* xr = xv + (size_t)node * 128;
            for (int k = 0; k < 128; k++)
                a = fmaf(xr[k], wqt[(size_t)k * 128 + col], a);
            qrow[col] = a;
        }
        __syncthreads();
        float4 qa = *(const float4*)&qrow[8 * j];
        float4 qb = *(const float4*)&qrow[8 * j + 4];
        int rs = rs_cv[node], re = rs_cv[node + 1];
        int cnt = re - rs;
        int per = (cnt + 3) >> 2;
        int e0 = rs + wid * per, e1 = min(e0 + per, re);
        float s = 0.f;
        float acc[8] = {};
        accum_g16(xqkv, csr_cv, e0, e1, g, qa, qb, s, acc);
        #pragma unroll
        for (int i = 0; i < 8; i++) {
            acc[i] += __shfl_xor(acc[i], 16, 64);
            acc[i] += __shfl_xor(acc[i], 32, 64);
        }
        s += __shfl_xor(s, 16, 64);
        s += __shfl_xor(s, 32, 64);
        if (g == 0) {
            *(float4*)&sm_a[wid * 128 + 8 * j]     = make_float4(acc[0], acc[1], acc[2], acc[3]);
            *(float4*)&sm_a[wid * 128 + 8 * j + 4] = make_float4(acc[4], acc[5], acc[6], acc[7]);
            if ((j & 3) == 0) sm_s[wid * 4 + (j >> 2)] = s;
        }
        __syncthreads();
        if (threadIdx.x < 64) {
            int lp = 2 * lane;
            int h = lp >> 5;
            float S = 0.f, AX = 0.f, AY = 0.f;
            #pragma unroll
            for (int i = 0; i < 4; i++) {
                S  += sm_s[i * 4 + h];
                float2 a2 = *(const float2*)&sm_a[i * 128 + lp];
                AX += a2.x;
                AY += a2.y;
            }
            float inv = (S > 0.f) ? 1.f / S : 0.f;
            int off = lp + 4 * h;   // padded
            orow[off]     = AX * inv;
            orow[off + 1] = AY * inv;
            int eo = lp & 31;
            const float* mr = mrel_cv + h * 1024 + eo;
            const float* rb = orow + 36 * h;
            float t0 = 0.f, t1 = 0.f;
            #pragma unroll
            for (int d = 0; d < 32; d++) {
                float a = rb[d];
                t0 = fmaf(a, mr[d * 32], t0);
                t1 = fmaf(a, mr[d * 32 + 1], t1);
            }
            aggv[(size_t)node * 128 + lp]     = gelu_tanh(t0);
            aggv[(size_t)node * 128 + lp + 1] = gelu_tanh(t1);
        }
    } else {
        // ---------------- cc nodes (4 per block, 1 wave each) ----------------
        float* rowbuf = smem;        // [4][144]
        int node = (blockIdx.x - N_V) * 4 + wid;
        if (node >= n_c) return;
        const float* qp = xqkv + (size_t)node * 384 + 8 * j;
        float4 qa = *(const float4*)qp, qb = *(const float4*)(qp + 4);
        int rs = rs_cc[node], re = rs_cc[node + 1];
        float s = 0.f;
        float acc[8] = {};
        accum_g16(xqkv, csr_cc, rs, re, g, qa, qb, s, acc);
        #pragma unroll
        for (int i = 0; i < 8; i++) {
            acc[i] += __shfl_xor(acc[i], 16, 64);
            acc[i] += __shfl_xor(acc[i], 32, 64);
        }
        s += __shfl_xor(s, 16, 64);
        s += __shfl_xor(s, 32, 64);
        float inv = (s > 0.f) ? 1.f / s : 0.f;
        float* rb_w = rowbuf + wid * 144;
        if (g == 0) {
            int off = 8 * j + 4 * (j >> 2);   // +4 pad per head
            float4 o0 = make_float4(acc[0] * inv, acc[1] * inv, acc[2] * inv, acc[3] * inv);
            float4 o1 = make_float4(acc[4] * inv, acc[5] * inv, acc[6] * inv, acc[7] * inv);
            *(float4*)&rb_w[off]     = o0;
            *(float4*)&rb_w[off + 4] = o1;
        }
        // intra-wave DS ordering: no barrier needed
        int lp = 2 * lane;
        int h = lp >> 5, eo = lp & 31;
        const float* mr = mrel_cc + h * 1024 + eo;
        const float* rb = rb_w + 36 * h;
        float t0 = 0.f, t1 = 0.f;
        #pragma unroll
        for (int d = 0; d < 32; d++) {
            float a = rb[d];
            t0 = fmaf(a, mr[d * 32], t0);
            t1 = fmaf(a, mr[d * 32 + 1], t1);
        }
        float2 o = make_float2(gelu_tanh(t0), gelu_tanh(t1));
        *(float2*)(xqkv + (size_t)node * 384 + lp) = o;
    }
}

// ---------------- out-conv scalar attention (block per vnode, max-free) --------
__global__ __launch_bounds__(256) void attn_out(
    const float* __restrict__ qo, const float* __restrict__ ko, const float* __restrict__ vo,
    const int* __restrict__ rowstart, const int* __restrict__ csr,
    const float* __restrict__ arel_o, const float* __restrict__ prel_o,
    const float* __restrict__ mrel_o, const float* __restrict__ Wa_o,
    const float* __restrict__ ba_o, float* __restrict__ outl)
{
    int node = blockIdx.x;
    float qs = qo[node] * arel_o[0] * prel_o[0];
    int rs = rowstart[node], re = rowstart[node + 1];
    float s = 0.f, a = 0.f;
    for (int e = rs + (int)threadIdx.x; e < re; e += 256) {
        int si = csr[e];
        float w = __expf(qs * ko[si]);
        s += w;
        a = fmaf(w, vo[si], a);
    }
    #pragma unroll
    for (int off = 32; off >= 1; off >>= 1) {
        s += __shfl_xor(s, off, 64);
        a += __shfl_xor(a, off, 64);
    }
    __shared__ float sms[4], sma[4];
    int lane = threadIdx.x & 63, wid = threadIdx.x >> 6;
    if (lane == 0) { sms[wid] = s; sma[wid] = a; }
    __syncthreads();
    if (threadIdx.x == 0) {
        float S = sms[0] + sms[1] + sms[2] + sms[3];
        float A = sma[0] + sma[1] + sma[2] + sma[3];
        float agg = (S > 0.f) ? A / S : 0.f;
        agg *= mrel_o[0];
        outl[node] = gelu_tanh(agg) * Wa_o[0] + ba_o[0];
    }
}

// ---------------- final head: JK-max -> node_fc -> MLP ------------------------
__global__ void final_head(const float* __restrict__ outs,
    const float* __restrict__ fc_W, const float* __restrict__ fc_b,
    const float* __restrict__ W1, const float* __restrict__ b1,
    const float* __restrict__ W2, const float* __restrict__ b2,
    float* __restrict__ out)
{
    int b = threadIdx.x;
    if (b >= 64) return;
    float h = fc_b[0];
    #pragma unroll
    for (int v = 0; v < 4; v++) {
        int n = b * 4 + v;
        float jk = fmaxf(fmaxf(outs[0 * N_V + n], outs[1 * N_V + n]), outs[2 * N_V + n]);
        h = fmaf(jk, fc_W[v], h);
    }
    h = gelu_tanh(h);
    float h0 = gelu_tanh(h * W1[0] + b1[0]);
    float h1 = gelu_tanh(h * W1[1] + b1[1]);
    out[b] = h0 * W2[0] + h1 * W2[1] + b2[0];
}

// ---------------- orchestration ----------------------------------------------
extern "C" void kernel_launch(void* const* d_in, const int* in_sizes, int n_in,
                              void* d_out, int out_size, void* d_ws, size_t ws_size,
                              hipStream_t stream) {
    (void)in_sizes; (void)n_in; (void)out_size; (void)ws_size;
    const float* x_cell  = (const float*)d_in[0];
    const float* x_vcell = (const float*)d_in[1];
    const float* Wk   = (const float*)d_in[2];
    const float* bk   = (const float*)d_in[3];
    const float* Wq   = (const float*)d_in[4];
    const float* bq   = (const float*)d_in[5];
    const float* Wv   = (const float*)d_in[6];
    const float* bv   = (const float*)d_in[7];
    const float* Wa   = (const float*)d_in[8];
    const float* ba   = (const float*)d_in[9];
    const float* skip = (const float*)d_in[10];
    const float* arel = (const float*)d_in[11];
    const float* mrel = (const float*)d_in[12];
    const float* prel = (const float*)d_in[13];
    const float* Wk_o = (const float*)d_in[14];
    const float* bk_o = (const float*)d_in[15];
    const float* Wq_o = (const float*)d_in[16];
    const float* bq_o = (const float*)d_in[17];
    const float* Wv_o = (const float*)d_in[18];
    const float* bv_o = (const float*)d_in[19];
    const float* Wa_o = (const float*)d_in[20];
    const float* ba_o = (const float*)d_in[21];
    const float* arel_o = (const float*)d_in[22];
    const float* mrel_o = (const float*)d_in[23];
    const float* prel_o = (const float*)d_in[24];
    const float* fc_W  = (const float*)d_in[25];
    const float* fc_b  = (const float*)d_in[26];
    const float* mlp_W1 = (const float*)d_in[27];
    const float* mlp_b1 = (const float*)d_in[28];
    const float* mlp_W2 = (const float*)d_in[29];
    const float* mlp_b2 = (const float*)d_in[30];
    const int* src_cc = (const int*)d_in[31];
    const int* dst_cc = (const int*)d_in[32];
    const int* src_cv = (const int*)d_in[33];
    const int* dst_cv = (const int*)d_in[34];

    // workspace carve-up (256B aligned)
    char* p = (char*)d_ws;
    auto alloc = [&](size_t bytes) -> char* {
        uintptr_t q = ((uintptr_t)p + 255) & ~(uintptr_t)255;
        p = (char*)(q + bytes);
        return (char*)q;
    };
    float* WQT  = (float*)alloc(sizeof(float) * NL * 2 * CH * CH);
    float* BQT  = (float*)alloc(sizeof(float) * NL * 2 * CH);
    float* XC   = (float*)alloc(sizeof(float) * (size_t)N_C * CH);
    float* XV   = (float*)alloc(sizeof(float) * (size_t)N_V * CH);
    float* XQKV = (float*)alloc(sizeof(float) * (size_t)N_C * 384);  // [q~|k|v] per node
    float* AGGV = (float*)alloc(sizeof(float) * (size_t)N_V * CH);
    float* KO   = (float*)alloc(sizeof(float) * N_C);
    float* VO   = (float*)alloc(sizeof(float) * N_C);
    float* QO   = (float*)alloc(sizeof(float) * N_V);
    float* OUTS = (float*)alloc(sizeof(float) * NL * N_V);
    // bf16x3 buffers
    short* XH   = (short*)alloc(sizeof(short) * (size_t)N_C * CH);
    short* XM   = (short*)alloc(sizeof(short) * (size_t)N_C * CH);
    short* XL   = (short*)alloc(sizeof(short) * (size_t)N_C * CH);
    short* WP   = (short*)alloc(sizeof(short) * (size_t)NL * 9 * CH * CH);
    // CSR-build scratch (hist region zeroed in one memset)
    int* bhist    = (int*)alloc(sizeof(int) * 512);
    int* bhist_cc = bhist;
    int* bhist_cv = bhist + 256;
    int* bbase_cc = (int*)alloc(sizeof(int) * 257);
    int* cur_cc   = (int*)alloc(sizeof(int) * 256);
    int* cur_cv   = (int*)alloc(sizeof(int) * 256);
    int* rs_cc    = (int*)alloc(sizeof(int) * (N_C + 1));
    int* rs_cv    = (int*)alloc(sizeof(int) * (N_V + 1));
    int* csr_cc   = (int*)alloc(sizeof(int) * NE1);
    int* csr_cv   = (int*)alloc(sizeof(int) * NE2);
    int2* tmp_cc  = (int2*)alloc(sizeof(int2) * NE1);

    // ---- setup: composed weights + splits + CSR ----
    compose_wq<<<CDIV(NL * 2 * (CH + 1) * CH, 256), 256, 0, stream>>>(
        Wq, bq, arel, prel, WQT, BQT);
    split_w<<<CDIV(NL * 3 * CH * CH, 256), 256, 0, stream>>>(WQT, Wk, Wv, WP);
    split_x<<<CDIV(N_C * CH, 256), 256, 0, stream>>>(x_cell, N_C * CH, XH, XM, XL);
    hipMemsetAsync(bhist, 0, sizeof(int) * 512, stream);
    bucket_hist<<<CDIV(NE1, EPB), 256, 0, stream>>>(dst_cc, NE1, 8, bhist_cc);
    bucket_hist<<<CDIV(NE2, EPB), 256, 0, stream>>>(dst_cv, NE2, 0, bhist_cv);
    scan256<<<1, 256, 0, stream>>>(bhist_cc, bbase_cc, cur_cc);
    scan256<<<1, 256, 0, stream>>>(bhist_cv, rs_cv, cur_cv);   // rs_cv IS the cv row starts
    partition_edges<true ><<<CDIV(NE1, EPB), 256, 0, stream>>>(src_cc, dst_cc, NE1, 8,
                                                               cur_cc, tmp_cc, nullptr);
    partition_edges<false><<<CDIV(NE2, EPB), 256, 0, stream>>>(src_cv, dst_cv, NE2, 0,
                                                               cur_cv, nullptr, csr_cv);
    bucket_finalize<<<CDIV(N_C, 256), 256, 0, stream>>>(tmp_cc, bbase_cc, N_C, NE1,
                                                        rs_cc, csr_cc);

    const int gb_c = CDIV(N_C, 64);             // 938
    const int gb_v = CDIV(N_V, 64);             // 4
    const int gb_attn = N_V + CDIV(N_C, 4);     // 256 cv + 15000 cc blocks

    for (int li = 0; li < NL; li++) {
        const float* xc_src = (li == 0) ? x_cell : XC;
        const float* xv_src = (li == 0) ? x_vcell : XV;
        size_t w0 = (size_t)(li * 2) * CH * CH;
        size_t w1 = (size_t)(li * 2 + 1) * CH * CH;
        int b0 = (li * 2) * CH, b1 = (li * 2 + 1) * CH;

        // bf16x3 MFMA q~/k/v GEMM (LDS-staged packed B) -> XQKV[n] = [q~|k|v]
        gemm_qkv_mfma<<<gb_c, 256, 0, stream>>>(XH, XM, XL,
                                                WP + (size_t)li * 9 * CH * CH,
                                                BQT + b0, bk + b0, bv + b0,
                                                XQKV, N_C);

        // unified attention: cv (inline q~v projection, 4 waves/node) + cc
        attn_uni<<<gb_attn, 256, 0, stream>>>(
            XQKV, xv_src, WQT + w1, BQT + b1,
            rs_cc, csr_cc, rs_cv, csr_cv,
            mrel + (size_t)(li * 2) * NH * HD * HD,
            mrel + (size_t)(li * 2 + 1) * NH * HD * HD,
            AGGV, N_C);

        // Wa GEMMs with skip epilogue; c-side fuses out-conv k/v + bf16x3 emit
        gemm128<<<gb_c, 256, 0, stream>>>(XQKV, 384, Wa + w0, ba + b0, XC, N_C,
                                          skip + li * 2, xc_src,
                                          Wk_o + li * CH, bk_o + li, KO,
                                          Wv_o + li * CH, bv_o + li, VO,
                                          (li < NL - 1) ? XH : nullptr,
                                          (li < NL - 1) ? XM : nullptr,
                                          (li < NL - 1) ? XL : nullptr);
        gemm128<<<gb_v, 256, 0, stream>>>(AGGV, 128, Wa + w1, ba + b1, XV, N_V,
                                          skip + li * 2 + 1, xv_src,
                                          Wq_o + li * CH, bq_o + li, QO,
                                          nullptr, nullptr, nullptr,
                                          nullptr, nullptr, nullptr);

        // out-conv scalar attention on cv edges
        attn_out<<<N_V, 256, 0, stream>>>(QO, KO, VO, rs_cv, csr_cv,
                                          arel_o + li, prel_o + li, mrel_o + li,
                                          Wa_o + li, ba_o + li, OUTS + li * N_V);
    }

    final_head<<<1, 64, 0, stream>>>(OUTS, fc_W, fc_b, mlp_W1, mlp_b1, mlp_W2, mlp_b2,
                                     (float*)d_out);
}

// Round 16
// 1009.786 us; speedup vs baseline: 1.5713x; 1.5713x over previous
//
#include <hip/hip_runtime.h>
#include <math.h>
#include <stdint.h>

#define N_C 60000
#define N_V 256
#define CH 128
#define NH 4
#define HD 32
#define NL 3
#define NE1 600000
#define NE2 240000

#define CDIV(a,b) (((a)+(b)-1)/(b))
#define EPB 1024   // elems per block in counting-sort kernels

__device__ __forceinline__ float gelu_tanh(float x) {
    float x3 = x * x * x;
    float t = tanhf(0.7978845608028654f * (x + 0.044715f * x3));
    return 0.5f * x * (1.0f + t);
}

__device__ __forceinline__ float dot8(float4 qa, float4 qb, float4 ka, float4 kb) {
    float d = qa.x * ka.x;
    d = fmaf(qa.y, ka.y, d);
    d = fmaf(qa.z, ka.z, d);
    d = fmaf(qa.w, ka.w, d);
    d = fmaf(qb.x, kb.x, d);
    d = fmaf(qb.y, kb.y, d);
    d = fmaf(qb.z, kb.z, d);
    d = fmaf(qb.w, kb.w, d);
    return d;
}

// ---------------- weight composition: W~q = Wq . arel  (prel/sqrt(D) folded) ---
__global__ __launch_bounds__(256) void compose_wq(
    const float* __restrict__ Wq, const float* __restrict__ bq,
    const float* __restrict__ arel, const float* __restrict__ prel,
    float* __restrict__ WQT, float* __restrict__ BQT)
{
    int gid = blockIdx.x * blockDim.x + threadIdx.x;
    const int total = NL * 2 * (CH + 1) * CH;
    if (gid >= total) return;
    int li2 = gid / ((CH + 1) * CH);
    int rem = gid % ((CH + 1) * CH);
    int c   = rem / CH;          // 0..CH ; CH => bias row
    int col = rem % CH;
    int h = col >> 5, d = col & 31;
    const float* ar = arel + (li2 * NH + h) * (HD * HD) + d * HD;  // [e]
    float scale = prel[li2 * NH + h] * 0.17677669529663687f;       // prel/sqrt(32)
    const float* src = (c < CH) ? (Wq + ((size_t)li2 * CH + c) * CH + h * HD)
                                : (bq + li2 * CH + h * HD);
    float acc = 0.f;
    #pragma unroll
    for (int e = 0; e < HD; e++) acc = fmaf(src[e], ar[e], acc);
    acc *= scale;
    if (c < CH) WQT[((size_t)li2 * CH + c) * CH + col] = acc;
    else        BQT[li2 * CH + col] = acc;
}

// ================= CSR build: two-level LDS counting sort =====================
__global__ __launch_bounds__(256) void bucket_hist(const int* __restrict__ dst, int E,
                                                   int shift, int* __restrict__ bhist)
{
    __shared__ int h[256];
    int t = threadIdx.x;
    h[t] = 0;
    __syncthreads();
    int i0 = blockIdx.x * EPB, i1 = min(i0 + EPB, E);
    for (int i = i0 + t; i < i1; i += 256)
        atomicAdd(&h[(dst[i] >> shift) & 255], 1);
    __syncthreads();
    if (h[t] > 0) atomicAdd(&bhist[t], h[t]);
}

__global__ __launch_bounds__(256) void scan256(const int* __restrict__ h,
                                               int* __restrict__ base, int* __restrict__ cur)
{
    __shared__ int p[256];
    int t = threadIdx.x;
    int v = h[t];
    p[t] = v;
    __syncthreads();
    for (int off = 1; off < 256; off <<= 1) {
        int u = (t >= off) ? p[t - off] : 0;
        __syncthreads();
        p[t] += u;
        __syncthreads();
    }
    base[t] = p[t] - v;
    cur[t]  = p[t] - v;
    if (t == 255) base[256] = p[255];
}

template<bool PAIR>
__global__ __launch_bounds__(256) void partition_edges(
    const int* __restrict__ src, const int* __restrict__ dst, int E, int shift,
    int* __restrict__ cur, int2* __restrict__ tmp_pair, int* __restrict__ out_src)
{
    __shared__ int cnt[256], base[256], cnt2[256];
    int t = threadIdx.x;
    cnt[t] = 0; cnt2[t] = 0;
    __syncthreads();
    int i0 = blockIdx.x * EPB, i1 = min(i0 + EPB, E);
    for (int i = i0 + t; i < i1; i += 256)
        atomicAdd(&cnt[(dst[i] >> shift) & 255], 1);
    __syncthreads();
    if (cnt[t] > 0) base[t] = atomicAdd(&cur[t], cnt[t]);
    __syncthreads();
    for (int i = i0 + t; i < i1; i += 256) {
        int d = dst[i];
        int dig = (d >> shift) & 255;
        int r = atomicAdd(&cnt2[dig], 1);
        int pos = base[dig] + r;
        if constexpr (PAIR) tmp_pair[pos] = make_int2(src[i], d);
        else                out_src[pos] = src[i];
    }
}

__global__ __launch_bounds__(256) void bucket_finalize(
    const int2* __restrict__ tmp, const int* __restrict__ bbase, int n, int NE,
    int* __restrict__ rs, int* __restrict__ csr)
{
    __shared__ int cnt[256], pre[256], cnt2[256];
    int b = blockIdx.x, t = threadIdx.x;
    int s0 = bbase[b], s1 = bbase[b + 1];
    cnt[t] = 0; cnt2[t] = 0;
    __syncthreads();
    for (int i = s0 + t; i < s1; i += 256)
        atomicAdd(&cnt[tmp[i].y & 255], 1);
    __syncthreads();
    int v = cnt[t];
    pre[t] = v;
    __syncthreads();
    for (int off = 1; off < 256; off <<= 1) {
        int u = (t >= off) ? pre[t - off] : 0;
        __syncthreads();
        pre[t] += u;
        __syncthreads();
    }
    pre[t] -= v;   // exclusive
    __syncthreads();
    int dstid = b * 256 + t;
    if (dstid < n) rs[dstid] = s0 + pre[t];
    if (b == 0 && t == 0) rs[n] = NE;
    for (int i = s0 + t; i < s1; i += 256) {
        int2 e = tmp[i];
        int low = e.y & 255;
        int r = atomicAdd(&cnt2[low], 1);
        csr[s0 + pre[low] + r] = e.x;
    }
}

// ---------------- fused q~/k/v GEMM; split cols tx*4 / 64+tx*4 (2-way banks) ---
__global__ __launch_bounds__(256) void gemm_qkv(
    const float* __restrict__ A, int lda, int M,
    const float* __restrict__ W0, const float* __restrict__ W1, const float* __restrict__ W2,
    const float* __restrict__ b0, const float* __restrict__ b1, const float* __restrict__ b2,
    float* __restrict__ out)
{
    __shared__ float As[64][132];   // 33 KB
    __shared__ float Bs[32][128];   // 16 KB
    int tid = threadIdx.x;
    int row0 = blockIdx.x * 64;
    int tx = tid & 15;   // cols tx*4..+3 and 64+tx*4..+3
    int ty = tid >> 4;   // rows ty*4..+3
    #pragma unroll
    for (int i = 0; i < 8; i++) {
        int slot = tid + i * 256;            // [0,2048) float4 slots
        int r = slot >> 5, kq = slot & 31;
        int rr = row0 + r;
        float4 v = make_float4(0.f, 0.f, 0.f, 0.f);
        if (rr < M) v = *(const float4*)(A + (size_t)rr * lda + kq * 4);
        *(float4*)&As[r][kq * 4] = v;
    }
    const float* Ws[3] = {W0, W1, W2};
    const float* bs[3] = {b0, b1, b2};
    for (int jw = 0; jw < 3; jw++) {
        float acc[4][8] = {};
        for (int k0 = 0; k0 < 128; k0 += 32) {
            __syncthreads();
            #pragma unroll
            for (int i = 0; i < 4; i++) {
                int slot = tid + i * 256;    // [0,1024)
                int kr = slot >> 5, cq = slot & 31;
                *(float4*)&Bs[kr][cq * 4] = *(const float4*)(Ws[jw] + (size_t)(k0 + kr) * 128 + cq * 4);
            }
            __syncthreads();
            #pragma unroll
            for (int k4 = 0; k4 < 32; k4 += 4) {
                float4 av[4];
                #pragma unroll
                for (int i = 0; i < 4; i++)
                    av[i] = *(const float4*)&As[ty * 4 + i][k0 + k4];
                #pragma unroll
                for (int kk = 0; kk < 4; kk++) {
                    float4 bl = *(const float4*)&Bs[k4 + kk][tx * 4];
                    float4 bh = *(const float4*)&Bs[k4 + kk][64 + tx * 4];
                    float bb[8] = {bl.x, bl.y, bl.z, bl.w, bh.x, bh.y, bh.z, bh.w};
                    #pragma unroll
                    for (int i = 0; i < 4; i++) {
                        float a = ((const float*)&av[i])[kk];
                        #pragma unroll
                        for (int j = 0; j < 8; j++)
                            acc[i][j] = fmaf(a, bb[j], acc[i][j]);
                    }
                }
            }
        }
        #pragma unroll
        for (int i = 0; i < 4; i++) {
            int r = row0 + ty * 4 + i;
            if (r >= M) continue;
            float4 o0 = make_float4(acc[i][0] + bs[jw][tx * 4 + 0],
                                    acc[i][1] + bs[jw][tx * 4 + 1],
                                    acc[i][2] + bs[jw][tx * 4 + 2],
                                    acc[i][3] + bs[jw][tx * 4 + 3]);
            float4 o1 = make_float4(acc[i][4] + bs[jw][64 + tx * 4 + 0],
                                    acc[i][5] + bs[jw][64 + tx * 4 + 1],
                                    acc[i][6] + bs[jw][64 + tx * 4 + 2],
                                    acc[i][7] + bs[jw][64 + tx * 4 + 3]);
            float* op = out + (size_t)r * 384 + jw * 128;
            *(float4*)(op + tx * 4) = o0;
            *(float4*)(op + 64 + tx * 4) = o1;
        }
    }
}

// ---------------- fp32 GEMM, split cols, + fused scalar projections ------------
// Merged dual dispatch: blocks [0,nblk1) run GEMM-1 (c-side), blocks >= nblk1
// run GEMM-2 (v-side). All parameter selection is wave-uniform.
__global__ __launch_bounds__(256) void gemm128(
    int nblk1,
    // primary (c-side)
    const float* __restrict__ A1, int lda1, const float* __restrict__ W1,
    const float* __restrict__ bias1, float* __restrict__ out1, int M1,
    const float* __restrict__ gate1, const float* __restrict__ xold1,
    const float* __restrict__ wk1, const float* __restrict__ bk1, float* __restrict__ ko1,
    const float* __restrict__ wv1, const float* __restrict__ bv1, float* __restrict__ vo1,
    // secondary (v-side)
    const float* __restrict__ A2, int lda2, const float* __restrict__ W2,
    const float* __restrict__ bias2, float* __restrict__ out2, int M2,
    const float* __restrict__ gate2, const float* __restrict__ xold2,
    const float* __restrict__ wk2, const float* __restrict__ bk2, float* __restrict__ ko2)
{
    __shared__ float As[64][36];    // 9 KB (32-wide k-tile, +4 pad)
    __shared__ float Bs[32][128];   // 16 KB
    bool sec = (blockIdx.x >= (unsigned)nblk1);
    const float* A    = sec ? A2 : A1;
    int lda           = sec ? lda2 : lda1;
    const float* W    = sec ? W2 : W1;
    const float* bias = sec ? bias2 : bias1;
    float* out        = sec ? out2 : out1;
    int M             = sec ? M2 : M1;
    const float* gate = sec ? gate2 : gate1;
    const float* xold = sec ? xold2 : xold1;
    const float* wk_o = sec ? wk2 : wk1;
    const float* bk_o = sec ? bk2 : bk1;
    float* ko         = sec ? ko2 : ko1;
    const float* wv_o = sec ? nullptr : wv1;
    const float* bv_o = sec ? nullptr : bv1;
    float* vo         = sec ? nullptr : vo1;

    int tid = threadIdx.x;
    int row0 = (sec ? (blockIdx.x - nblk1) : blockIdx.x) * 64;
    int tx = tid & 15;
    int ty = tid >> 4;
    float acc[4][8] = {};
    for (int k0 = 0; k0 < 128; k0 += 32) {
        __syncthreads();
        #pragma unroll
        for (int i = 0; i < 2; i++) {
            int slot = tid + i * 256;            // [0,512) float4 slots
            int r = slot >> 3, kq = slot & 7;
            int rr = row0 + r;
            float4 v = make_float4(0.f, 0.f, 0.f, 0.f);
            if (rr < M) v = *(const float4*)(A + (size_t)rr * lda + k0 + kq * 4);
            *(float4*)&As[r][kq * 4] = v;
        }
        #pragma unroll
        for (int i = 0; i < 4; i++) {
            int slot = tid + i * 256;            // [0,1024)
            int kr = slot >> 5, cq = slot & 31;
            *(float4*)&Bs[kr][cq * 4] = *(const float4*)(W + (size_t)(k0 + kr) * 128 + cq * 4);
        }
        __syncthreads();
        #pragma unroll
        for (int k4 = 0; k4 < 32; k4 += 4) {
            float4 av[4];
            #pragma unroll
            for (int i = 0; i < 4; i++)
                av[i] = *(const float4*)&As[ty * 4 + i][k4];
            #pragma unroll
            for (int kk = 0; kk < 4; kk++) {
                float4 bl = *(const float4*)&Bs[k4 + kk][tx * 4];
                float4 bh = *(const float4*)&Bs[k4 + kk][64 + tx * 4];
                float bb[8] = {bl.x, bl.y, bl.z, bl.w, bh.x, bh.y, bh.z, bh.w};
                #pragma unroll
                for (int i = 0; i < 4; i++) {
                    float a = ((const float*)&av[i])[kk];
                    #pragma unroll
                    for (int j = 0; j < 8; j++)
                        acc[i][j] = fmaf(a, bb[j], acc[i][j]);
                }
            }
        }
    }
    float g = 1.f, og = 0.f;
    if (gate != nullptr) { g = 1.f / (1.f + expf(-gate[0])); og = 1.f - g; }
    float wkr[8], wvr[8];
    if (wk_o != nullptr) {
        #pragma unroll
        for (int j = 0; j < 4; j++) {
            wkr[j]     = wk_o[tx * 4 + j];
            wkr[4 + j] = wk_o[64 + tx * 4 + j];
        }
    }
    if (wv_o != nullptr) {
        #pragma unroll
        for (int j = 0; j < 4; j++) {
            wvr[j]     = wv_o[tx * 4 + j];
            wvr[4 + j] = wv_o[64 + tx * 4 + j];
        }
    }
    #pragma unroll
    for (int i = 0; i < 4; i++) {
        int r = row0 + ty * 4 + i;
        if (r >= M) continue;   // uniform across each 16-lane group
        float vals[8];
        #pragma unroll
        for (int j = 0; j < 4; j++) {
            float v0 = acc[i][j]     + bias[tx * 4 + j];
            float v1 = acc[i][4 + j] + bias[64 + tx * 4 + j];
            if (gate != nullptr) {
                v0 = g * v0 + og * xold[(size_t)r * 128 + tx * 4 + j];
                v1 = g * v1 + og * xold[(size_t)r * 128 + 64 + tx * 4 + j];
            }
            vals[j] = v0;
            vals[4 + j] = v1;
        }
        float* op = out + (size_t)r * 128;
        *(float4*)(op + tx * 4)      = make_float4(vals[0], vals[1], vals[2], vals[3]);
        *(float4*)(op + 64 + tx * 4) = make_float4(vals[4], vals[5], vals[6], vals[7]);
        if (wk_o != nullptr) {
            float pk = 0.f, pv = 0.f;
            #pragma unroll
            for (int j = 0; j < 8; j++) pk = fmaf(vals[j], wkr[j], pk);
            if (wv_o != nullptr) {
                #pragma unroll
                for (int j = 0; j < 8; j++) pv = fmaf(vals[j], wvr[j], pv);
            }
            #pragma unroll
            for (int off = 1; off < 16; off <<= 1) {
                pk += __shfl_xor(pk, off, 64);
                if (wv_o != nullptr) pv += __shfl_xor(pv, off, 64);
            }
            if (tx == 0) {
                ko[r] = pk + bk_o[0];
                if (wv_o != nullptr) vo[r] = pv + bv_o[0];
            }
        }
    }
}

// ---------------- group-of-16 edge accumulation (4 edges in flight + 2x unroll)
__device__ __forceinline__ void accum_g16(
    const float* __restrict__ xqkv, const int* __restrict__ csr,
    int e0, int e1, int g, float4 qa, float4 qb, float& s_io, float acc[8])
{
    float s = 0.f;
    int e = e0 + g;
    for (; e + 4 < e1; e += 8) {
        int i0 = csr[e], i1 = csr[e + 4];
        const float* p0 = xqkv + (size_t)i0 * 384 + 128 + ((threadIdx.x & 15) * 8);
        const float* p1 = xqkv + (size_t)i1 * 384 + 128 + ((threadIdx.x & 15) * 8);
        float4 k0a = *(const float4*)p0,         k0b = *(const float4*)(p0 + 4);
        float4 v0a = *(const float4*)(p0 + 128), v0b = *(const float4*)(p0 + 132);
        float4 k1a = *(const float4*)p1,         k1b = *(const float4*)(p1 + 4);
        float4 v1a = *(const float4*)(p1 + 128), v1b = *(const float4*)(p1 + 132);
        float d0 = dot8(qa, qb, k0a, k0b);
        float d1 = dot8(qa, qb, k1a, k1b);
        d0 += __shfl_xor(d0, 1, 64); d1 += __shfl_xor(d1, 1, 64);
        d0 += __shfl_xor(d0, 2, 64); d1 += __shfl_xor(d1, 2, 64);
        float w0 = __expf(d0), w1 = __expf(d1);
        s += w0 + w1;
        acc[0] = fmaf(w0, v0a.x, acc[0]); acc[0] = fmaf(w1, v1a.x, acc[0]);
        acc[1] = fmaf(w0, v0a.y, acc[1]); acc[1] = fmaf(w1, v1a.y, acc[1]);
        acc[2] = fmaf(w0, v0a.z, acc[2]); acc[2] = fmaf(w1, v1a.z, acc[2]);
        acc[3] = fmaf(w0, v0a.w, acc[3]); acc[3] = fmaf(w1, v1a.w, acc[3]);
        acc[4] = fmaf(w0, v0b.x, acc[4]); acc[4] = fmaf(w1, v1b.x, acc[4]);
        acc[5] = fmaf(w0, v0b.y, acc[5]); acc[5] = fmaf(w1, v1b.y, acc[5]);
        acc[6] = fmaf(w0, v0b.z, acc[6]); acc[6] = fmaf(w1, v1b.z, acc[6]);
        acc[7] = fmaf(w0, v0b.w, acc[7]); acc[7] = fmaf(w1, v1b.w, acc[7]);
    }
    if (e < e1) {
        int i0 = csr[e];
        const float* p0 = xqkv + (size_t)i0 * 384 + 128 + ((threadIdx.x & 15) * 8);
        float4 k0a = *(const float4*)p0,         k0b = *(const float4*)(p0 + 4);
        float4 v0a = *(const float4*)(p0 + 128), v0b = *(const float4*)(p0 + 132);
        float d0 = dot8(qa, qb, k0a, k0b);
        d0 += __shfl_xor(d0, 1, 64);
        d0 += __shfl_xor(d0, 2, 64);
        float w0 = __expf(d0);
        s += w0;
        acc[0] = fmaf(w0, v0a.x, acc[0]);
        acc[1] = fmaf(w0, v0a.y, acc[1]);
        acc[2] = fmaf(w0, v0a.z, acc[2]);
        acc[3] = fmaf(w0, v0a.w, acc[3]);
        acc[4] = fmaf(w0, v0b.x, acc[4]);
        acc[5] = fmaf(w0, v0b.y, acc[5]);
        acc[6] = fmaf(w0, v0b.z, acc[6]);
        acc[7] = fmaf(w0, v0b.w, acc[7]);
    }
    s_io = s;
}

// ---------------- unified attention: cv blocks [0,256) + cc blocks -------------
__global__ __launch_bounds__(256) void attn_uni(
    float* xqkv,
    const float* __restrict__ xv, const float* __restrict__ wqt,
    const float* __restrict__ bqt,
    const int* __restrict__ rs_cc, const int* __restrict__ csr_cc,
    const int* __restrict__ rs_cv, const int* __restrict__ csr_cv,
    const float* __restrict__ mrel_cc, const float* __restrict__ mrel_cv,
    float* __restrict__ aggv, int n_c)
{
    __shared__ float smem[800];   // 3.2 KB, carved per role
    int lane = threadIdx.x & 63, wid = threadIdx.x >> 6;
    int g = lane >> 4, j = lane & 15;

    if (blockIdx.x < N_V) {
        // ---------------- cv node ----------------
        int node = blockIdx.x;
        float* qrow = smem;          // [128]
        float* sm_s = smem + 128;    // [4][4]
        float* sm_a = smem + 144;    // [4][128]
        float* orow = smem + 656;    // [144]
        if (wid < 2) {
            int col = wid * 64 + lane;
            float a = bqt[col];
            const float* xr = xv + (size_t)node * 128;
            for (int k = 0; k < 128; k++)
                a = fmaf(xr[k], wqt[(size_t)k * 128 + col], a);
            qrow[col] = a;
        }
        __syncthreads();
        float4 qa = *(const float4*)&qrow[8 * j];
        float4 qb = *(const float4*)&qrow[8 * j + 4];
        int rs = rs_cv[node], re = rs_cv[node + 1];
        int cnt = re - rs;
        int per = (cnt + 3) >> 2;
        int e0 = rs + wid * per, e1 = min(e0 + per, re);
        float s = 0.f;
        float acc[8] = {};
        accum_g16(xqkv, csr_cv, e0, e1, g, qa, qb, s, acc);
        #pragma unroll
        for (int i = 0; i < 8; i++) {
            acc[i] += __shfl_xor(acc[i], 16, 64);
            acc[i] += __shfl_xor(acc[i], 32, 64);
        }
        s += __shfl_xor(s, 16, 64);
        s += __shfl_xor(s, 32, 64);
        if (g == 0) {
            *(float4*)&sm_a[wid * 128 + 8 * j]     = make_float4(acc[0], acc[1], acc[2], acc[3]);
            *(float4*)&sm_a[wid * 128 + 8 * j + 4] = make_float4(acc[4], acc[5], acc[6], acc[7]);
            if ((j & 3) == 0) sm_s[wid * 4 + (j >> 2)] = s;
        }
        __syncthreads();
        if (threadIdx.x < 64) {
            int lp = 2 * lane;
            int h = lp >> 5;
            float S = 0.f, AX = 0.f, AY = 0.f;
            #pragma unroll
            for (int i = 0; i < 4; i++) {
                S  += sm_s[i * 4 + h];
                float2 a2 = *(const float2*)&sm_a[i * 128 + lp];
                AX += a2.x;
                AY += a2.y;
            }
            float inv = (S > 0.f) ? 1.f / S : 0.f;
            int off = lp + 4 * h;   // padded
            orow[off]     = AX * inv;
            orow[off + 1] = AY * inv;
            int eo = lp & 31;
            const float* mr = mrel_cv + h * 1024 + eo;
            const float* rb = orow + 36 * h;
            float t0 = 0.f, t1 = 0.f;
            #pragma unroll
            for (int d = 0; d < 32; d++) {
                float a = rb[d];
                t0 = fmaf(a, mr[d * 32], t0);
                t1 = fmaf(a, mr[d * 32 + 1], t1);
            }
            aggv[(size_t)node * 128 + lp]     = gelu_tanh(t0);
            aggv[(size_t)node * 128 + lp + 1] = gelu_tanh(t1);
        }
    } else {
        // ---------------- cc nodes (4 per block, 1 wave each) ----------------
        float* rowbuf = smem;        // [4][144]
        int node = (blockIdx.x - N_V) * 4 + wid;
        if (node >= n_c) return;
        const float* qp = xqkv + (size_t)node * 384 + 8 * j;
        float4 qa = *(const float4*)qp, qb = *(const float4*)(qp + 4);
        int rs = rs_cc[node], re = rs_cc[node + 1];
        float s = 0.f;
        float acc[8] = {};
        accum_g16(xqkv, csr_cc, rs, re, g, qa, qb, s, acc);
        #pragma unroll
        for (int i = 0; i < 8; i++) {
            acc[i] += __shfl_xor(acc[i], 16, 64);
            acc[i] += __shfl_xor(acc[i], 32, 64);
        }
        s += __shfl_xor(s, 16, 64);
        s += __shfl_xor(s, 32, 64);
        float inv = (s > 0.f) ? 1.f / s : 0.f;
        float* rb_w = rowbuf + wid * 144;
        if (g == 0) {
            int off = 8 * j + 4 * (j >> 2);   // +4 pad per head
            float4 o0 = make_float4(acc[0] * inv, acc[1] * inv, acc[2] * inv, acc[3] * inv);
            float4 o1 = make_float4(acc[4] * inv, acc[5] * inv, acc[6] * inv, acc[7] * inv);
            *(float4*)&rb_w[off]     = o0;
            *(float4*)&rb_w[off + 4] = o1;
        }
        // intra-wave DS ordering: no barrier needed
        int lp = 2 * lane;
        int h = lp >> 5, eo = lp & 31;
        const float* mr = mrel_cc + h * 1024 + eo;
        const float* rb = rb_w + 36 * h;
        float t0 = 0.f, t1 = 0.f;
        #pragma unroll
        for (int d = 0; d < 32; d++) {
            float a = rb[d];
            t0 = fmaf(a, mr[d * 32], t0);
            t1 = fmaf(a, mr[d * 32 + 1], t1);
        }
        float2 o = make_float2(gelu_tanh(t0), gelu_tanh(t1));
        *(float2*)(xqkv + (size_t)node * 384 + lp) = o;
    }
}

// ---------------- out-conv scalar attention (block per vnode, max-free) --------
__global__ __launch_bounds__(256) void attn_out(
    const float* __restrict__ qo, const float* __restrict__ ko, const float* __restrict__ vo,
    const int* __restrict__ rowstart, const int* __restrict__ csr,
    const float* __restrict__ arel_o, const float* __restrict__ prel_o,
    const float* __restrict__ mrel_o, const float* __restrict__ Wa_o,
    const float* __restrict__ ba_o, float* __restrict__ outl)
{
    int node = blockIdx.x;
    float qs = qo[node] * arel_o[0] * prel_o[0];
    int rs = rowstart[node], re = rowstart[node + 1];
    float s = 0.f, a = 0.f;
    for (int e = rs + (int)threadIdx.x; e < re; e += 256) {
        int si = csr[e];
        float w = __expf(qs * ko[si]);
        s += w;
        a = fmaf(w, vo[si], a);
    }
    #pragma unroll
    for (int off = 32; off >= 1; off >>= 1) {
        s += __shfl_xor(s, off, 64);
        a += __shfl_xor(a, off, 64);
    }
    __shared__ float sms[4], sma[4];
    int lane = threadIdx.x & 63, wid = threadIdx.x >> 6;
    if (lane == 0) { sms[wid] = s; sma[wid] = a; }
    __syncthreads();
    if (threadIdx.x == 0) {
        float S = sms[0] + sms[1] + sms[2] + sms[3];
        float A = sma[0] + sma[1] + sma[2] + sma[3];
        float agg = (S > 0.f) ? A / S : 0.f;
        agg *= mrel_o[0];
        outl[node] = gelu_tanh(agg) * Wa_o[0] + ba_o[0];
    }
}

// ---------------- final head: JK-max -> node_fc -> MLP ------------------------
__global__ void final_head(const float* __restrict__ outs,
    const float* __restrict__ fc_W, const float* __restrict__ fc_b,
    const float* __restrict__ W1, const float* __restrict__ b1,
    const float* __restrict__ W2, const float* __restrict__ b2,
    float* __restrict__ out)
{
    int b = threadIdx.x;
    if (b >= 64) return;
    float h = fc_b[0];
    #pragma unroll
    for (int v = 0; v < 4; v++) {
        int n = b * 4 + v;
        float jk = fmaxf(fmaxf(outs[0 * N_V + n], outs[1 * N_V + n]), outs[2 * N_V + n]);
        h = fmaf(jk, fc_W[v], h);
    }
    h = gelu_tanh(h);
    float h0 = gelu_tanh(h * W1[0] + b1[0]);
    float h1 = gelu_tanh(h * W1[1] + b1[1]);
    out[b] = h0 * W2[0] + h1 * W2[1] + b2[0];
}

// ---------------- orchestration ----------------------------------------------
extern "C" void kernel_launch(void* const* d_in, const int* in_sizes, int n_in,
                              void* d_out, int out_size, void* d_ws, size_t ws_size,
                              hipStream_t stream) {
    (void)in_sizes; (void)n_in; (void)out_size; (void)ws_size;
    const float* x_cell  = (const float*)d_in[0];
    const float* x_vcell = (const float*)d_in[1];
    const float* Wk   = (const float*)d_in[2];
    const float* bk   = (const float*)d_in[3];
    const float* Wq   = (const float*)d_in[4];
    const float* bq   = (const float*)d_in[5];
    const float* Wv   = (const float*)d_in[6];
    const float* bv   = (const float*)d_in[7];
    const float* Wa   = (const float*)d_in[8];
    const float* ba   = (const float*)d_in[9];
    const float* skip = (const float*)d_in[10];
    const float* arel = (const float*)d_in[11];
    const float* mrel = (const float*)d_in[12];
    const float* prel = (const float*)d_in[13];
    const float* Wk_o = (const float*)d_in[14];
    const float* bk_o = (const float*)d_in[15];
    const float* Wq_o = (const float*)d_in[16];
    const float* bq_o = (const float*)d_in[17];
    const float* Wv_o = (const float*)d_in[18];
    const float* bv_o = (const float*)d_in[19];
    const float* Wa_o = (const float*)d_in[20];
    const float* ba_o = (const float*)d_in[21];
    const float* arel_o = (const float*)d_in[22];
    const float* mrel_o = (const float*)d_in[23];
    const float* prel_o = (const float*)d_in[24];
    const float* fc_W  = (const float*)d_in[25];
    const float* fc_b  = (const float*)d_in[26];
    const float* mlp_W1 = (const float*)d_in[27];
    const float* mlp_b1 = (const float*)d_in[28];
    const float* mlp_W2 = (const float*)d_in[29];
    const float* mlp_b2 = (const float*)d_in[30];
    const int* src_cc = (const int*)d_in[31];
    const int* dst_cc = (const int*)d_in[32];
    const int* src_cv = (const int*)d_in[33];
    const int* dst_cv = (const int*)d_in[34];

    // workspace carve-up (256B aligned)
    char* p = (char*)d_ws;
    auto alloc = [&](size_t bytes) -> char* {
        uintptr_t q = ((uintptr_t)p + 255) & ~(uintptr_t)255;
        p = (char*)(q + bytes);
        return (char*)q;
    };
    float* WQT  = (float*)alloc(sizeof(float) * NL * 2 * CH * CH);
    float* BQT  = (float*)alloc(sizeof(float) * NL * 2 * CH);
    float* XC   = (float*)alloc(sizeof(float) * (size_t)N_C * CH);
    float* XV   = (float*)alloc(sizeof(float) * (size_t)N_V * CH);
    float* XQKV = (float*)alloc(sizeof(float) * (size_t)N_C * 384);  // [q~|k|v] per node
    float* AGGV = (float*)alloc(sizeof(float) * (size_t)N_V * CH);
    float* KO   = (float*)alloc(sizeof(float) * N_C);
    float* VO   = (float*)alloc(sizeof(float) * N_C);
    float* QO   = (float*)alloc(sizeof(float) * N_V);
    float* OUTS = (float*)alloc(sizeof(float) * NL * N_V);
    // CSR-build scratch (hist region zeroed in one memset)
    int* bhist    = (int*)alloc(sizeof(int) * 512);
    int* bhist_cc = bhist;
    int* bhist_cv = bhist + 256;
    int* bbase_cc = (int*)alloc(sizeof(int) * 257);
    int* cur_cc   = (int*)alloc(sizeof(int) * 256);
    int* cur_cv   = (int*)alloc(sizeof(int) * 256);
    int* rs_cc    = (int*)alloc(sizeof(int) * (N_C + 1));
    int* rs_cv    = (int*)alloc(sizeof(int) * (N_V + 1));
    int* csr_cc   = (int*)alloc(sizeof(int) * NE1);
    int* csr_cv   = (int*)alloc(sizeof(int) * NE2);
    int2* tmp_cc  = (int2*)alloc(sizeof(int2) * NE1);

    // ---- setup: composed weights + CSR (two-level counting sort) ----
    compose_wq<<<CDIV(NL * 2 * (CH + 1) * CH, 256), 256, 0, stream>>>(
        Wq, bq, arel, prel, WQT, BQT);
    hipMemsetAsync(bhist, 0, sizeof(int) * 512, stream);
    bucket_hist<<<CDIV(NE1, EPB), 256, 0, stream>>>(dst_cc, NE1, 8, bhist_cc);
    bucket_hist<<<CDIV(NE2, EPB), 256, 0, stream>>>(dst_cv, NE2, 0, bhist_cv);
    scan256<<<1, 256, 0, stream>>>(bhist_cc, bbase_cc, cur_cc);
    scan256<<<1, 256, 0, stream>>>(bhist_cv, rs_cv, cur_cv);   // rs_cv IS the cv row starts
    partition_edges<true ><<<CDIV(NE1, EPB), 256, 0, stream>>>(src_cc, dst_cc, NE1, 8,
                                                               cur_cc, tmp_cc, nullptr);
    partition_edges<false><<<CDIV(NE2, EPB), 256, 0, stream>>>(src_cv, dst_cv, NE2, 0,
                                                               cur_cv, nullptr, csr_cv);
    bucket_finalize<<<CDIV(N_C, 256), 256, 0, stream>>>(tmp_cc, bbase_cc, N_C, NE1,
                                                        rs_cc, csr_cc);

    const int gb_c = CDIV(N_C, 64);             // 938
    const int gb_v = CDIV(N_V, 64);             // 4
    const int gb_attn = N_V + CDIV(N_C, 4);     // 256 cv + 15000 cc blocks

    for (int li = 0; li < NL; li++) {
        const float* xc_src = (li == 0) ? x_cell : XC;
        const float* xv_src = (li == 0) ? x_vcell : XV;
        size_t w0 = (size_t)(li * 2) * CH * CH;
        size_t w1 = (size_t)(li * 2 + 1) * CH * CH;
        int b0 = (li * 2) * CH, b1 = (li * 2 + 1) * CH;

        // fused q~/k/v GEMM -> XQKV[n] = [q~|k|v]
        gemm_qkv<<<gb_c, 256, 0, stream>>>(xc_src, 128, N_C,
                                           WQT + w0, Wk + w0, Wv + w0,
                                           BQT + b0, bk + b0, bv + b0, XQKV);

        // unified attention: cv (inline q~v projection, 4 waves/node) + cc
        attn_uni<<<gb_attn, 256, 0, stream>>>(
            XQKV, xv_src, WQT + w1, BQT + b1,
            rs_cc, csr_cc, rs_cv, csr_cv,
            mrel + (size_t)(li * 2) * NH * HD * HD,
            mrel + (size_t)(li * 2 + 1) * NH * HD * HD,
            AGGV, N_C);

        // merged Wa GEMMs (c-side + v-side in one dispatch) with skip epilogue;
        // c-side fuses out-conv k/v projections, v-side fuses q projection
        gemm128<<<gb_c + gb_v, 256, 0, stream>>>(
            gb_c,
            XQKV, 384, Wa + w0, ba + b0, XC, N_C,
            skip + li * 2, xc_src,
            Wk_o + li * CH, bk_o + li, KO,
            Wv_o + li * CH, bv_o + li, VO,
            AGGV, 128, Wa + w1, ba + b1, XV, N_V,
            skip + li * 2 + 1, xv_src,
            Wq_o + li * CH, bq_o + li, QO);

        // out-conv scalar attention on cv edges
        attn_out<<<N_V, 256, 0, stream>>>(QO, KO, VO, rs_cv, csr_cv,
                                          arel_o + li, prel_o + li, mrel_o + li,
                                          Wa_o + li, ba_o + li, OUTS + li * N_V);
    }

    final_head<<<1, 64, 0, stream>>>(OUTS, fc_W, fc_b, mlp_W1, mlp_b1, mlp_W2, mlp_b2,
                                     (float*)d_out);
}

// Round 17
// 1005.419 us; speedup vs baseline: 1.5781x; 1.0043x over previous
//
#include <hip/hip_runtime.h>
#include <math.h>
#include <stdint.h>

#define N_C 60000
#define N_V 256
#define CH 128
#define NH 4
#define HD 32
#define NL 3
#define NE1 600000
#define NE2 240000

#define CDIV(a,b) (((a)+(b)-1)/(b))
#define EPB 1024   // elems per block in counting-sort kernels

__device__ __forceinline__ float gelu_tanh(float x) {
    float x3 = x * x * x;
    float t = tanhf(0.7978845608028654f * (x + 0.044715f * x3));
    return 0.5f * x * (1.0f + t);
}

__device__ __forceinline__ float dot8(float4 qa, float4 qb, float4 ka, float4 kb) {
    float d = qa.x * ka.x;
    d = fmaf(qa.y, ka.y, d);
    d = fmaf(qa.z, ka.z, d);
    d = fmaf(qa.w, ka.w, d);
    d = fmaf(qb.x, kb.x, d);
    d = fmaf(qb.y, kb.y, d);
    d = fmaf(qb.z, kb.z, d);
    d = fmaf(qb.w, kb.w, d);
    return d;
}

// ---------------- weight composition: W~q = Wq . arel  (prel/sqrt(D) folded) ---
__global__ __launch_bounds__(256) void compose_wq(
    const float* __restrict__ Wq, const float* __restrict__ bq,
    const float* __restrict__ arel, const float* __restrict__ prel,
    float* __restrict__ WQT, float* __restrict__ BQT)
{
    int gid = blockIdx.x * blockDim.x + threadIdx.x;
    const int total = NL * 2 * (CH + 1) * CH;
    if (gid >= total) return;
    int li2 = gid / ((CH + 1) * CH);
    int rem = gid % ((CH + 1) * CH);
    int c   = rem / CH;          // 0..CH ; CH => bias row
    int col = rem % CH;
    int h = col >> 5, d = col & 31;
    const float* ar = arel + (li2 * NH + h) * (HD * HD) + d * HD;  // [e]
    float scale = prel[li2 * NH + h] * 0.17677669529663687f;       // prel/sqrt(32)
    const float* src = (c < CH) ? (Wq + ((size_t)li2 * CH + c) * CH + h * HD)
                                : (bq + li2 * CH + h * HD);
    float acc = 0.f;
    #pragma unroll
    for (int e = 0; e < HD; e++) acc = fmaf(src[e], ar[e], acc);
    acc *= scale;
    if (c < CH) WQT[((size_t)li2 * CH + c) * CH + col] = acc;
    else        BQT[li2 * CH + col] = acc;
}

// ================= CSR build: two-level LDS counting sort =====================
__global__ __launch_bounds__(256) void bucket_hist(const int* __restrict__ dst, int E,
                                                   int shift, int* __restrict__ bhist)
{
    __shared__ int h[256];
    int t = threadIdx.x;
    h[t] = 0;
    __syncthreads();
    int i0 = blockIdx.x * EPB, i1 = min(i0 + EPB, E);
    for (int i = i0 + t; i < i1; i += 256)
        atomicAdd(&h[(dst[i] >> shift) & 255], 1);
    __syncthreads();
    if (h[t] > 0) atomicAdd(&bhist[t], h[t]);
}

__global__ __launch_bounds__(256) void scan256(const int* __restrict__ h,
                                               int* __restrict__ base, int* __restrict__ cur)
{
    __shared__ int p[256];
    int t = threadIdx.x;
    int v = h[t];
    p[t] = v;
    __syncthreads();
    for (int off = 1; off < 256; off <<= 1) {
        int u = (t >= off) ? p[t - off] : 0;
        __syncthreads();
        p[t] += u;
        __syncthreads();
    }
    base[t] = p[t] - v;
    cur[t]  = p[t] - v;
    if (t == 255) base[256] = p[255];
}

template<bool PAIR>
__global__ __launch_bounds__(256) void partition_edges(
    const int* __restrict__ src, const int* __restrict__ dst, int E, int shift,
    int* __restrict__ cur, int2* __restrict__ tmp_pair, int* __restrict__ out_src)
{
    __shared__ int cnt[256], base[256], cnt2[256];
    int t = threadIdx.x;
    cnt[t] = 0; cnt2[t] = 0;
    __syncthreads();
    int i0 = blockIdx.x * EPB, i1 = min(i0 + EPB, E);
    for (int i = i0 + t; i < i1; i += 256)
        atomicAdd(&cnt[(dst[i] >> shift) & 255], 1);
    __syncthreads();
    if (cnt[t] > 0) base[t] = atomicAdd(&cur[t], cnt[t]);
    __syncthreads();
    for (int i = i0 + t; i < i1; i += 256) {
        int d = dst[i];
        int dig = (d >> shift) & 255;
        int r = atomicAdd(&cnt2[dig], 1);
        int pos = base[dig] + r;
        if constexpr (PAIR) tmp_pair[pos] = make_int2(src[i], d);
        else                out_src[pos] = src[i];
    }
}

__global__ __launch_bounds__(256) void bucket_finalize(
    const int2* __restrict__ tmp, const int* __restrict__ bbase, int n, int NE,
    int* __restrict__ rs, int* __restrict__ csr)
{
    __shared__ int cnt[256], pre[256], cnt2[256];
    int b = blockIdx.x, t = threadIdx.x;
    int s0 = bbase[b], s1 = bbase[b + 1];
    cnt[t] = 0; cnt2[t] = 0;
    __syncthreads();
    for (int i = s0 + t; i < s1; i += 256)
        atomicAdd(&cnt[tmp[i].y & 255], 1);
    __syncthreads();
    int v = cnt[t];
    pre[t] = v;
    __syncthreads();
    for (int off = 1; off < 256; off <<= 1) {
        int u = (t >= off) ? pre[t - off] : 0;
        __syncthreads();
        pre[t] += u;
        __syncthreads();
    }
    pre[t] -= v;   // exclusive
    __syncthreads();
    int dstid = b * 256 + t;
    if (dstid < n) rs[dstid] = s0 + pre[t];
    if (b == 0 && t == 0) rs[n] = NE;
    for (int i = s0 + t; i < s1; i += 256) {
        int2 e = tmp[i];
        int low = e.y & 255;
        int r = atomicAdd(&cnt2[low], 1);
        csr[s0 + pre[low] + r] = e.x;
    }
}

// ---------------- fused q~/k/v GEMM + tail blocks run prev-layer attn_out ------
__global__ __launch_bounds__(256) void gemm_qkv(
    int nblk1,
    const float* __restrict__ A, int lda, int M,
    const float* __restrict__ W0, const float* __restrict__ W1, const float* __restrict__ W2,
    const float* __restrict__ b0, const float* __restrict__ b1, const float* __restrict__ b2,
    float* __restrict__ out,
    // prev-layer out-conv attention (tail blocks); unused when grid == nblk1
    const float* __restrict__ qo, const float* __restrict__ ko, const float* __restrict__ vo,
    const int* __restrict__ rs_cv, const int* __restrict__ csr_cv,
    const float* __restrict__ arel_o, const float* __restrict__ prel_o,
    const float* __restrict__ mrel_o, const float* __restrict__ Wa_o,
    const float* __restrict__ ba_o, float* __restrict__ outl)
{
    __shared__ float As[64][132];   // 33 KB
    __shared__ float Bs[32][128];   // 16 KB
    __shared__ float sms[4], sma[4];
    int tid = threadIdx.x;

    if ((int)blockIdx.x >= nblk1) {
        // ---------------- prev-layer out-conv scalar attention ----------------
        int node = blockIdx.x - nblk1;
        float qs = qo[node] * arel_o[0] * prel_o[0];
        int rs = rs_cv[node], re = rs_cv[node + 1];
        float s = 0.f, a = 0.f;
        for (int e = rs + tid; e < re; e += 256) {
            int si = csr_cv[e];
            float w = __expf(qs * ko[si]);
            s += w;
            a = fmaf(w, vo[si], a);
        }
        #pragma unroll
        for (int off = 32; off >= 1; off >>= 1) {
            s += __shfl_xor(s, off, 64);
            a += __shfl_xor(a, off, 64);
        }
        int lane = tid & 63, wid = tid >> 6;
        if (lane == 0) { sms[wid] = s; sma[wid] = a; }
        __syncthreads();
        if (tid == 0) {
            float S = sms[0] + sms[1] + sms[2] + sms[3];
            float A_ = sma[0] + sma[1] + sma[2] + sma[3];
            float agg = (S > 0.f) ? A_ / S : 0.f;
            agg *= mrel_o[0];
            outl[node] = gelu_tanh(agg) * Wa_o[0] + ba_o[0];
        }
        return;
    }

    int row0 = blockIdx.x * 64;
    int tx = tid & 15;   // cols tx*4..+3 and 64+tx*4..+3
    int ty = tid >> 4;   // rows ty*4..+3
    #pragma unroll
    for (int i = 0; i < 8; i++) {
        int slot = tid + i * 256;            // [0,2048) float4 slots
        int r = slot >> 5, kq = slot & 31;
        int rr = row0 + r;
        float4 v = make_float4(0.f, 0.f, 0.f, 0.f);
        if (rr < M) v = *(const float4*)(A + (size_t)rr * lda + kq * 4);
        *(float4*)&As[r][kq * 4] = v;
    }
    const float* Ws[3] = {W0, W1, W2};
    const float* bs[3] = {b0, b1, b2};
    for (int jw = 0; jw < 3; jw++) {
        float acc[4][8] = {};
        for (int k0 = 0; k0 < 128; k0 += 32) {
            __syncthreads();
            #pragma unroll
            for (int i = 0; i < 4; i++) {
                int slot = tid + i * 256;    // [0,1024)
                int kr = slot >> 5, cq = slot & 31;
                *(float4*)&Bs[kr][cq * 4] = *(const float4*)(Ws[jw] + (size_t)(k0 + kr) * 128 + cq * 4);
            }
            __syncthreads();
            #pragma unroll
            for (int k4 = 0; k4 < 32; k4 += 4) {
                float4 av[4];
                #pragma unroll
                for (int i = 0; i < 4; i++)
                    av[i] = *(const float4*)&As[ty * 4 + i][k0 + k4];
                #pragma unroll
                for (int kk = 0; kk < 4; kk++) {
                    float4 bl = *(const float4*)&Bs[k4 + kk][tx * 4];
                    float4 bh = *(const float4*)&Bs[k4 + kk][64 + tx * 4];
                    float bb[8] = {bl.x, bl.y, bl.z, bl.w, bh.x, bh.y, bh.z, bh.w};
                    #pragma unroll
                    for (int i = 0; i < 4; i++) {
                        float a = ((const float*)&av[i])[kk];
                        #pragma unroll
                        for (int j = 0; j < 8; j++)
                            acc[i][j] = fmaf(a, bb[j], acc[i][j]);
                    }
                }
            }
        }
        #pragma unroll
        for (int i = 0; i < 4; i++) {
            int r = row0 + ty * 4 + i;
            if (r >= M) continue;
            float4 o0 = make_float4(acc[i][0] + bs[jw][tx * 4 + 0],
                                    acc[i][1] + bs[jw][tx * 4 + 1],
                                    acc[i][2] + bs[jw][tx * 4 + 2],
                                    acc[i][3] + bs[jw][tx * 4 + 3]);
            float4 o1 = make_float4(acc[i][4] + bs[jw][64 + tx * 4 + 0],
                                    acc[i][5] + bs[jw][64 + tx * 4 + 1],
                                    acc[i][6] + bs[jw][64 + tx * 4 + 2],
                                    acc[i][7] + bs[jw][64 + tx * 4 + 3]);
            float* op = out + (size_t)r * 384 + jw * 128;
            *(float4*)(op + tx * 4) = o0;
            *(float4*)(op + 64 + tx * 4) = o1;
        }
    }
}

// ---------------- fp32 GEMM, split cols, + fused scalar projections ------------
// Merged dual dispatch: blocks [0,nblk1) run GEMM-1 (c-side), blocks >= nblk1
// run GEMM-2 (v-side). All parameter selection is wave-uniform.
__global__ __launch_bounds__(256) void gemm128(
    int nblk1,
    // primary (c-side)
    const float* __restrict__ A1, int lda1, const float* __restrict__ W1,
    const float* __restrict__ bias1, float* __restrict__ out1, int M1,
    const float* __restrict__ gate1, const float* __restrict__ xold1,
    const float* __restrict__ wk1, const float* __restrict__ bk1, float* __restrict__ ko1,
    const float* __restrict__ wv1, const float* __restrict__ bv1, float* __restrict__ vo1,
    // secondary (v-side)
    const float* __restrict__ A2, int lda2, const float* __restrict__ W2,
    const float* __restrict__ bias2, float* __restrict__ out2, int M2,
    const float* __restrict__ gate2, const float* __restrict__ xold2,
    const float* __restrict__ wk2, const float* __restrict__ bk2, float* __restrict__ ko2)
{
    __shared__ float As[64][36];    // 9 KB (32-wide k-tile, +4 pad)
    __shared__ float Bs[32][128];   // 16 KB
    bool sec = (blockIdx.x >= (unsigned)nblk1);
    const float* A    = sec ? A2 : A1;
    int lda           = sec ? lda2 : lda1;
    const float* W    = sec ? W2 : W1;
    const float* bias = sec ? bias2 : bias1;
    float* out        = sec ? out2 : out1;
    int M             = sec ? M2 : M1;
    const float* gate = sec ? gate2 : gate1;
    const float* xold = sec ? xold2 : xold1;
    const float* wk_o = sec ? wk2 : wk1;
    const float* bk_o = sec ? bk2 : bk1;
    float* ko         = sec ? ko2 : ko1;
    const float* wv_o = sec ? nullptr : wv1;
    const float* bv_o = sec ? nullptr : bv1;
    float* vo         = sec ? nullptr : vo1;

    int tid = threadIdx.x;
    int row0 = (sec ? (blockIdx.x - nblk1) : blockIdx.x) * 64;
    int tx = tid & 15;
    int ty = tid >> 4;
    float acc[4][8] = {};
    for (int k0 = 0; k0 < 128; k0 += 32) {
        __syncthreads();
        #pragma unroll
        for (int i = 0; i < 2; i++) {
            int slot = tid + i * 256;            // [0,512) float4 slots
            int r = slot >> 3, kq = slot & 7;
            int rr = row0 + r;
            float4 v = make_float4(0.f, 0.f, 0.f, 0.f);
            if (rr < M) v = *(const float4*)(A + (size_t)rr * lda + k0 + kq * 4);
            *(float4*)&As[r][kq * 4] = v;
        }
        #pragma unroll
        for (int i = 0; i < 4; i++) {
            int slot = tid + i * 256;            // [0,1024)
            int kr = slot >> 5, cq = slot & 31;
            *(float4*)&Bs[kr][cq * 4] = *(const float4*)(W + (size_t)(k0 + kr) * 128 + cq * 4);
        }
        __syncthreads();
        #pragma unroll
        for (int k4 = 0; k4 < 32; k4 += 4) {
            float4 av[4];
            #pragma unroll
            for (int i = 0; i < 4; i++)
                av[i] = *(const float4*)&As[ty * 4 + i][k4];
            #pragma unroll
            for (int kk = 0; kk < 4; kk++) {
                float4 bl = *(const float4*)&Bs[k4 + kk][tx * 4];
                float4 bh = *(const float4*)&Bs[k4 + kk][64 + tx * 4];
                float bb[8] = {bl.x, bl.y, bl.z, bl.w, bh.x, bh.y, bh.z, bh.w};
                #pragma unroll
                for (int i = 0; i < 4; i++) {
                    float a = ((const float*)&av[i])[kk];
                    #pragma unroll
                    for (int j = 0; j < 8; j++)
                        acc[i][j] = fmaf(a, bb[j], acc[i][j]);
                }
            }
        }
    }
    float g = 1.f, og = 0.f;
    if (gate != nullptr) { g = 1.f / (1.f + expf(-gate[0])); og = 1.f - g; }
    float wkr[8], wvr[8];
    if (wk_o != nullptr) {
        #pragma unroll
        for (int j = 0; j < 4; j++) {
            wkr[j]     = wk_o[tx * 4 + j];
            wkr[4 + j] = wk_o[64 + tx * 4 + j];
        }
    }
    if (wv_o != nullptr) {
        #pragma unroll
        for (int j = 0; j < 4; j++) {
            wvr[j]     = wv_o[tx * 4 + j];
            wvr[4 + j] = wv_o[64 + tx * 4 + j];
        }
    }
    #pragma unroll
    for (int i = 0; i < 4; i++) {
        int r = row0 + ty * 4 + i;
        if (r >= M) continue;   // uniform across each 16-lane group
        float vals[8];
        #pragma unroll
        for (int j = 0; j < 4; j++) {
            float v0 = acc[i][j]     + bias[tx * 4 + j];
            float v1 = acc[i][4 + j] + bias[64 + tx * 4 + j];
            if (gate != nullptr) {
                v0 = g * v0 + og * xold[(size_t)r * 128 + tx * 4 + j];
                v1 = g * v1 + og * xold[(size_t)r * 128 + 64 + tx * 4 + j];
            }
            vals[j] = v0;
            vals[4 + j] = v1;
        }
        float* op = out + (size_t)r * 128;
        *(float4*)(op + tx * 4)      = make_float4(vals[0], vals[1], vals[2], vals[3]);
        *(float4*)(op + 64 + tx * 4) = make_float4(vals[4], vals[5], vals[6], vals[7]);
        if (wk_o != nullptr) {
            float pk = 0.f, pv = 0.f;
            #pragma unroll
            for (int j = 0; j < 8; j++) pk = fmaf(vals[j], wkr[j], pk);
            if (wv_o != nullptr) {
                #pragma unroll
                for (int j = 0; j < 8; j++) pv = fmaf(vals[j], wvr[j], pv);
            }
            #pragma unroll
            for (int off = 1; off < 16; off <<= 1) {
                pk += __shfl_xor(pk, off, 64);
                if (wv_o != nullptr) pv += __shfl_xor(pv, off, 64);
            }
            if (tx == 0) {
                ko[r] = pk + bk_o[0];
                if (wv_o != nullptr) vo[r] = pv + bv_o[0];
            }
        }
    }
}

// ---------------- group-of-16 edge accumulation (4 edges in flight + 2x unroll)
__device__ __forceinline__ void accum_g16(
    const float* __restrict__ xqkv, const int* __restrict__ csr,
    int e0, int e1, int g, float4 qa, float4 qb, float& s_io, float acc[8])
{
    float s = 0.f;
    int e = e0 + g;
    for (; e + 4 < e1; e += 8) {
        int i0 = csr[e], i1 = csr[e + 4];
        const float* p0 = xqkv + (size_t)i0 * 384 + 128 + ((threadIdx.x & 15) * 8);
        const float* p1 = xqkv + (size_t)i1 * 384 + 128 + ((threadIdx.x & 15) * 8);
        float4 k0a = *(const float4*)p0,         k0b = *(const float4*)(p0 + 4);
        float4 v0a = *(const float4*)(p0 + 128), v0b = *(const float4*)(p0 + 132);
        float4 k1a = *(const float4*)p1,         k1b = *(const float4*)(p1 + 4);
        float4 v1a = *(const float4*)(p1 + 128), v1b = *(const float4*)(p1 + 132);
        float d0 = dot8(qa, qb, k0a, k0b);
        float d1 = dot8(qa, qb, k1a, k1b);
        d0 += __shfl_xor(d0, 1, 64); d1 += __shfl_xor(d1, 1, 64);
        d0 += __shfl_xor(d0, 2, 64); d1 += __shfl_xor(d1, 2, 64);
        float w0 = __expf(d0), w1 = __expf(d1);
        s += w0 + w1;
        acc[0] = fmaf(w0, v0a.x, acc[0]); acc[0] = fmaf(w1, v1a.x, acc[0]);
        acc[1] = fmaf(w0, v0a.y, acc[1]); acc[1] = fmaf(w1, v1a.y, acc[1]);
        acc[2] = fmaf(w0, v0a.z, acc[2]); acc[2] = fmaf(w1, v1a.z, acc[2]);
        acc[3] = fmaf(w0, v0a.w, acc[3]); acc[3] = fmaf(w1, v1a.w, acc[3]);
        acc[4] = fmaf(w0, v0b.x, acc[4]); acc[4] = fmaf(w1, v1b.x, acc[4]);
        acc[5] = fmaf(w0, v0b.y, acc[5]); acc[5] = fmaf(w1, v1b.y, acc[5]);
        acc[6] = fmaf(w0, v0b.z, acc[6]); acc[6] = fmaf(w1, v1b.z, acc[6]);
        acc[7] = fmaf(w0, v0b.w, acc[7]); acc[7] = fmaf(w1, v1b.w, acc[7]);
    }
    if (e < e1) {
        int i0 = csr[e];
        const float* p0 = xqkv + (size_t)i0 * 384 + 128 + ((threadIdx.x & 15) * 8);
        float4 k0a = *(const float4*)p0,         k0b = *(const float4*)(p0 + 4);
        float4 v0a = *(const float4*)(p0 + 128), v0b = *(const float4*)(p0 + 132);
        float d0 = dot8(qa, qb, k0a, k0b);
        d0 += __shfl_xor(d0, 1, 64);
        d0 += __shfl_xor(d0, 2, 64);
        float w0 = __expf(d0);
        s += w0;
        acc[0] = fmaf(w0, v0a.x, acc[0]);
        acc[1] = fmaf(w0, v0a.y, acc[1]);
        acc[2] = fmaf(w0, v0a.z, acc[2]);
        acc[3] = fmaf(w0, v0a.w, acc[3]);
        acc[4] = fmaf(w0, v0b.x, acc[4]);
        acc[5] = fmaf(w0, v0b.y, acc[5]);
        acc[6] = fmaf(w0, v0b.z, acc[6]);
        acc[7] = fmaf(w0, v0b.w, acc[7]);
    }
    s_io = s;
}

// ---------------- unified attention: cv blocks [0,256) + cc blocks -------------
__global__ __launch_bounds__(256) void attn_uni(
    float* xqkv,
    const float* __restrict__ xv, const float* __restrict__ wqt,
    const float* __restrict__ bqt,
    const int* __restrict__ rs_cc, const int* __restrict__ csr_cc,
    const int* __restrict__ rs_cv, const int* __restrict__ csr_cv,
    const float* __restrict__ mrel_cc, const float* __restrict__ mrel_cv,
    float* __restrict__ aggv, int n_c)
{
    __shared__ float smem[800];   // 3.2 KB, carved per role
    int lane = threadIdx.x & 63, wid = threadIdx.x >> 6;
    int g = lane >> 4, j = lane & 15;

    if (blockIdx.x < N_V) {
        // ---------------- cv node ----------------
        int node = blockIdx.x;
        float* qrow = smem;          // [128]
        float* sm_s = smem + 128;    // [4][4]
        float* sm_a = smem + 144;    // [4][128]
        float* orow = smem + 656;    // [144]
        if (wid < 2) {
            int col = wid * 64 + lane;
            float a = bqt[col];
            const float* xr = xv + (size_t)node * 128;
            for (int k = 0; k < 128; k++)
                a = fmaf(xr[k], wqt[(size_t)k * 128 + col], a);
            qrow[col] = a;
        }
        __syncthreads();
        float4 qa = *(const float4*)&qrow[8 * j];
        float4 qb = *(const float4*)&qrow[8 * j + 4];
        int rs = rs_cv[node], re = rs_cv[node + 1];
        int cnt = re - rs;
        int per = (cnt + 3) >> 2;
        int e0 = rs + wid * per, e1 = min(e0 + per, re);
        float s = 0.f;
        float acc[8] = {};
        accum_g16(xqkv, csr_cv, e0, e1, g, qa, qb, s, acc);
        #pragma unroll
        for (int i = 0; i < 8; i++) {
            acc[i] += __shfl_xor(acc[i], 16, 64);
            acc[i] += __shfl_xor(acc[i], 32, 64);
        }
        s += __shfl_xor(s, 16, 64);
        s += __shfl_xor(s, 32, 64);
        if (g == 0) {
            *(float4*)&sm_a[wid * 128 + 8 * j]     = make_float4(acc[0], acc[1], acc[2], acc[3]);
            *(float4*)&sm_a[wid * 128 + 8 * j + 4] = make_float4(acc[4], acc[5], acc[6], acc[7]);
            if ((j & 3) == 0) sm_s[wid * 4 + (j >> 2)] = s;
        }
        __syncthreads();
        if (threadIdx.x < 64) {
            int lp = 2 * lane;
            int h = lp >> 5;
            float S = 0.f, AX = 0.f, AY = 0.f;
            #pragma unroll
            for (int i = 0; i < 4; i++) {
                S  += sm_s[i * 4 + h];
                float2 a2 = *(const float2*)&sm_a[i * 128 + lp];
                AX += a2.x;
                AY += a2.y;
            }
            float inv = (S > 0.f) ? 1.f / S : 0.f;
            int off = lp + 4 * h;   // padded
            orow[off]     = AX * inv;
            orow[off + 1] = AY * inv;
            int eo = lp & 31;
            const float* mr = mrel_cv + h * 1024 + eo;
            const float* rb = orow + 36 * h;
            float t0 = 0.f, t1 = 0.f;
            #pragma unroll
            for (int d = 0; d < 32; d++) {
                float a = rb[d];
                t0 = fmaf(a, mr[d * 32], t0);
                t1 = fmaf(a, mr[d * 32 + 1], t1);
            }
            aggv[(size_t)node * 128 + lp]     = gelu_tanh(t0);
            aggv[(size_t)node * 128 + lp + 1] = gelu_tanh(t1);
        }
    } else {
        // ---------------- cc nodes (4 per block, 1 wave each) ----------------
        float* rowbuf = smem;        // [4][144]
        int node = (blockIdx.x - N_V) * 4 + wid;
        if (node >= n_c) return;
        const float* qp = xqkv + (size_t)node * 384 + 8 * j;
        float4 qa = *(const float4*)qp, qb = *(const float4*)(qp + 4);
        int rs = rs_cc[node], re = rs_cc[node + 1];
        float s = 0.f;
        float acc[8] = {};
        accum_g16(xqkv, csr_cc, rs, re, g, qa, qb, s, acc);
        #pragma unroll
        for (int i = 0; i < 8; i++) {
            acc[i] += __shfl_xor(acc[i], 16, 64);
            acc[i] += __shfl_xor(acc[i], 32, 64);
        }
        s += __shfl_xor(s, 16, 64);
        s += __shfl_xor(s, 32, 64);
        float inv = (s > 0.f) ? 1.f / s : 0.f;
        float* rb_w = rowbuf + wid * 144;
        if (g == 0) {
            int off = 8 * j + 4 * (j >> 2);   // +4 pad per head
            float4 o0 = make_float4(acc[0] * inv, acc[1] * inv, acc[2] * inv, acc[3] * inv);
            float4 o1 = make_float4(acc[4] * inv, acc[5] * inv, acc[6] * inv, acc[7] * inv);
            *(float4*)&rb_w[off]     = o0;
            *(float4*)&rb_w[off + 4] = o1;
        }
        // intra-wave DS ordering: no barrier needed
        int lp = 2 * lane;
        int h = lp >> 5, eo = lp & 31;
        const float* mr = mrel_cc + h * 1024 + eo;
        const float* rb = rb_w + 36 * h;
        float t0 = 0.f, t1 = 0.f;
        #pragma unroll
        for (int d = 0; d < 32; d++) {
            float a = rb[d];
            t0 = fmaf(a, mr[d * 32], t0);
            t1 = fmaf(a, mr[d * 32 + 1], t1);
        }
        float2 o = make_float2(gelu_tanh(t0), gelu_tanh(t1));
        *(float2*)(xqkv + (size_t)node * 384 + lp) = o;
    }
}

// ---------------- out-conv scalar attention (standalone, last layer) -----------
__global__ __launch_bounds__(256) void attn_out(
    const float* __restrict__ qo, const float* __restrict__ ko, const float* __restrict__ vo,
    const int* __restrict__ rowstart, const int* __restrict__ csr,
    const float* __restrict__ arel_o, const float* __restrict__ prel_o,
    const float* __restrict__ mrel_o, const float* __restrict__ Wa_o,
    const float* __restrict__ ba_o, float* __restrict__ outl)
{
    int node = blockIdx.x;
    float qs = qo[node] * arel_o[0] * prel_o[0];
    int rs = rowstart[node], re = rowstart[node + 1];
    float s = 0.f, a = 0.f;
    for (int e = rs + (int)threadIdx.x; e < re; e += 256) {
        int si = csr[e];
        float w = __expf(qs * ko[si]);
        s += w;
        a = fmaf(w, vo[si], a);
    }
    #pragma unroll
    for (int off = 32; off >= 1; off >>= 1) {
        s += __shfl_xor(s, off, 64);
        a += __shfl_xor(a, off, 64);
    }
    __shared__ float sms[4], sma[4];
    int lane = threadIdx.x & 63, wid = threadIdx.x >> 6;
    if (lane == 0) { sms[wid] = s; sma[wid] = a; }
    __syncthreads();
    if (threadIdx.x == 0) {
        float S = sms[0] + sms[1] + sms[2] + sms[3];
        float A = sma[0] + sma[1] + sma[2] + sma[3];
        float agg = (S > 0.f) ? A / S : 0.f;
        agg *= mrel_o[0];
        outl[node] = gelu_tanh(agg) * Wa_o[0] + ba_o[0];
    }
}

// ---------------- final head: JK-max -> node_fc -> MLP ------------------------
__global__ void final_head(const float* __restrict__ outs,
    const float* __restrict__ fc_W, const float* __restrict__ fc_b,
    const float* __restrict__ W1, const float* __restrict__ b1,
    const float* __restrict__ W2, const float* __restrict__ b2,
    float* __restrict__ out)
{
    int b = threadIdx.x;
    if (b >= 64) return;
    float h = fc_b[0];
    #pragma unroll
    for (int v = 0; v < 4; v++) {
        int n = b * 4 + v;
        float jk = fmaxf(fmaxf(outs[0 * N_V + n], outs[1 * N_V + n]), outs[2 * N_V + n]);
        h = fmaf(jk, fc_W[v], h);
    }
    h = gelu_tanh(h);
    float h0 = gelu_tanh(h * W1[0] + b1[0]);
    float h1 = gelu_tanh(h * W1[1] + b1[1]);
    out[b] = h0 * W2[0] + h1 * W2[1] + b2[0];
}

// ---------------- orchestration ----------------------------------------------
extern "C" void kernel_launch(void* const* d_in, const int* in_sizes, int n_in,
                              void* d_out, int out_size, void* d_ws, size_t ws_size,
                              hipStream_t stream) {
    (void)in_sizes; (void)n_in; (void)out_size; (void)ws_size;
    const float* x_cell  = (const float*)d_in[0];
    const float* x_vcell = (const float*)d_in[1];
    const float* Wk   = (const float*)d_in[2];
    const float* bk   = (const float*)d_in[3];
    const float* Wq   = (const float*)d_in[4];
    const float* bq   = (const float*)d_in[5];
    const float* Wv   = (const float*)d_in[6];
    const float* bv   = (const float*)d_in[7];
    const float* Wa   = (const float*)d_in[8];
    const float* ba   = (const float*)d_in[9];
    const float* skip = (const float*)d_in[10];
    const float* arel = (const float*)d_in[11];
    const float* mrel = (const float*)d_in[12];
    const float* prel = (const float*)d_in[13];
    const float* Wk_o = (const float*)d_in[14];
    const float* bk_o = (const float*)d_in[15];
    const float* Wq_o = (const float*)d_in[16];
    const float* bq_o = (const float*)d_in[17];
    const float* Wv_o = (const float*)d_in[18];
    const float* bv_o = (const float*)d_in[19];
    const float* Wa_o = (const float*)d_in[20];
    const float* ba_o = (const float*)d_in[21];
    const float* arel_o = (const float*)d_in[22];
    const float* mrel_o = (const float*)d_in[23];
    const float* prel_o = (const float*)d_in[24];
    const float* fc_W  = (const float*)d_in[25];
    const float* fc_b  = (const float*)d_in[26];
    const float* mlp_W1 = (const float*)d_in[27];
    const float* mlp_b1 = (const float*)d_in[28];
    const float* mlp_W2 = (const float*)d_in[29];
    const float* mlp_b2 = (const float*)d_in[30];
    const int* src_cc = (const int*)d_in[31];
    const int* dst_cc = (const int*)d_in[32];
    const int* src_cv = (const int*)d_in[33];
    const int* dst_cv = (const int*)d_in[34];

    // workspace carve-up (256B aligned)
    char* p = (char*)d_ws;
    auto alloc = [&](size_t bytes) -> char* {
        uintptr_t q = ((uintptr_t)p + 255) & ~(uintptr_t)255;
        p = (char*)(q + bytes);
        return (char*)q;
    };
    float* WQT  = (float*)alloc(sizeof(float) * NL * 2 * CH * CH);
    float* BQT  = (float*)alloc(sizeof(float) * NL * 2 * CH);
    float* XC   = (float*)alloc(sizeof(float) * (size_t)N_C * CH);
    float* XV   = (float*)alloc(sizeof(float) * (size_t)N_V * CH);
    float* XQKV = (float*)alloc(sizeof(float) * (size_t)N_C * 384);  // [q~|k|v] per node
    float* AGGV = (float*)alloc(sizeof(float) * (size_t)N_V * CH);
    float* KO   = (float*)alloc(sizeof(float) * N_C);
    float* VO   = (float*)alloc(sizeof(float) * N_C);
    float* QO   = (float*)alloc(sizeof(float) * N_V);
    float* OUTS = (float*)alloc(sizeof(float) * NL * N_V);
    // CSR-build scratch (hist region zeroed in one memset)
    int* bhist    = (int*)alloc(sizeof(int) * 512);
    int* bhist_cc = bhist;
    int* bhist_cv = bhist + 256;
    int* bbase_cc = (int*)alloc(sizeof(int) * 257);
    int* cur_cc   = (int*)alloc(sizeof(int) * 256);
    int* cur_cv   = (int*)alloc(sizeof(int) * 256);
    int* rs_cc    = (int*)alloc(sizeof(int) * (N_C + 1));
    int* rs_cv    = (int*)alloc(sizeof(int) * (N_V + 1));
    int* csr_cc   = (int*)alloc(sizeof(int) * NE1);
    int* csr_cv   = (int*)alloc(sizeof(int) * NE2);
    int2* tmp_cc  = (int2*)alloc(sizeof(int2) * NE1);

    // ---- setup: composed weights + CSR (two-level counting sort) ----
    compose_wq<<<CDIV(NL * 2 * (CH + 1) * CH, 256), 256, 0, stream>>>(
        Wq, bq, arel, prel, WQT, BQT);
    hipMemsetAsync(bhist, 0, sizeof(int) * 512, stream);
    bucket_hist<<<CDIV(NE1, EPB), 256, 0, stream>>>(dst_cc, NE1, 8, bhist_cc);
    bucket_hist<<<CDIV(NE2, EPB), 256, 0, stream>>>(dst_cv, NE2, 0, bhist_cv);
    scan256<<<1, 256, 0, stream>>>(bhist_cc, bbase_cc, cur_cc);
    scan256<<<1, 256, 0, stream>>>(bhist_cv, rs_cv, cur_cv);   // rs_cv IS the cv row starts
    partition_edges<true ><<<CDIV(NE1, EPB), 256, 0, stream>>>(src_cc, dst_cc, NE1, 8,
                                                               cur_cc, tmp_cc, nullptr);
    partition_edges<false><<<CDIV(NE2, EPB), 256, 0, stream>>>(src_cv, dst_cv, NE2, 0,
                                                               cur_cv, nullptr, csr_cv);
    bucket_finalize<<<CDIV(N_C, 256), 256, 0, stream>>>(tmp_cc, bbase_cc, N_C, NE1,
                                                        rs_cc, csr_cc);

    const int gb_c = CDIV(N_C, 64);             // 938
    const int gb_v = CDIV(N_V, 64);             // 4
    const int gb_attn = N_V + CDIV(N_C, 4);     // 256 cv + 15000 cc blocks

    for (int li = 0; li < NL; li++) {
        const float* xc_src = (li == 0) ? x_cell : XC;
        const float* xv_src = (li == 0) ? x_vcell : XV;
        size_t w0 = (size_t)(li * 2) * CH * CH;
        size_t w1 = (size_t)(li * 2 + 1) * CH * CH;
        int b0 = (li * 2) * CH, b1 = (li * 2 + 1) * CH;

        // fused q~/k/v GEMM; layers >0 append prev-layer out-conv attention tail
        int tail = (li > 0) ? N_V : 0;
        gemm_qkv<<<gb_c + tail, 256, 0, stream>>>(
            gb_c, xc_src, 128, N_C,
            WQT + w0, Wk + w0, Wv + w0,
            BQT + b0, bk + b0, bv + b0, XQKV,
            QO, KO, VO, rs_cv, csr_cv,
            arel_o + (li - 1), prel_o + (li - 1), mrel_o + (li - 1),
            Wa_o + (li - 1), ba_o + (li - 1),
            (li > 0) ? (OUTS + (li - 1) * N_V) : nullptr);

        // unified attention: cv (inline q~v projection, 4 waves/node) + cc
        attn_uni<<<gb_attn, 256, 0, stream>>>(
            XQKV, xv_src, WQT + w1, BQT + b1,
            rs_cc, csr_cc, rs_cv, csr_cv,
            mrel + (size_t)(li * 2) * NH * HD * HD,
            mrel + (size_t)(li * 2 + 1) * NH * HD * HD,
            AGGV, N_C);

        // merged Wa GEMMs (c-side + v-side in one dispatch) with skip epilogue;
        // c-side fuses out-conv k/v projections, v-side fuses q projection
        gemm128<<<gb_c + gb_v, 256, 0, stream>>>(
            gb_c,
            XQKV, 384, Wa + w0, ba + b0, XC, N_C,
            skip + li * 2, xc_src,
            Wk_o + li * CH, bk_o + li, KO,
            Wv_o + li * CH, bv_o + li, VO,
            AGGV, 128, Wa + w1, ba + b1, XV, N_V,
            skip + li * 2 + 1, xv_src,
            Wq_o + li * CH, bq_o + li, QO);
    }

    // last layer's out-conv attention, then final head
    attn_out<<<N_V, 256, 0, stream>>>(QO, KO, VO, rs_cv, csr_cv,
                                      arel_o + (NL - 1), prel_o + (NL - 1), mrel_o + (NL - 1),
                                      Wa_o + (NL - 1), ba_o + (NL - 1), OUTS + (NL - 1) * N_V);
    final_head<<<1, 64, 0, stream>>>(OUTS, fc_W, fc_b, mlp_W1, mlp_b1, mlp_W2, mlp_b2,
                                     (float*)d_out);
}